// Round 10
// baseline (79.439 us; speedup 1.0000x reference)
//
#include <hip/hip_runtime.h>

// Shapes: B=4, N1=N2=128, D=256, R=4, E=D/2=128
// Pipeline (4 dispatches):
//   1 k_proj_w2 : h1p/h2 projections (fp16 out) + W2/f2/Wa1/Wa2 fp16 fragment swizzles
//   2 k_scores  : scores via fp16 MFMA, 2x2 micro-tile per wave
//   3 k_softrel : softmax + rel via fp16 MFMA -> all_rel packed fp16 row-major
//   4 k_mlp     : fused MLP, both layers fp16 MFMA (hidden staged fp16 in LDS)

typedef _Float16 f16x8 __attribute__((ext_vector_type(8)));
typedef float f32x16 __attribute__((ext_vector_type(16)));

static __device__ __forceinline__ ushort f2h(float f) {
  _Float16 h = (_Float16)f;
  return __builtin_bit_cast(ushort, h);
}
static __device__ __forceinline__ uint pack2(float a, float b) {
  return (uint)f2h(a) | ((uint)f2h(b) << 16);
}
static __device__ __forceinline__ uint pk_add(uint a, uint b) {
  uint r;
  asm("v_pk_add_f16 %0, %1, %2" : "=v"(r) : "v"(a), "v"(b));
  return r;
}
static __device__ __forceinline__ uint pk_relu(uint a) {
  uint r;
  asm("v_pk_max_f16 %0, %1, %2" : "=v"(r) : "v"(a), "v"(0u));
  return r;
}

// ---------------- prep: projection (z<32) + fragment swizzles (z=32..35) ----------------
__global__ __launch_bounds__(256) void k_proj_w2(
    const float* __restrict__ f1, const float* __restrict__ f2,
    const float* __restrict__ W1, const float* __restrict__ b1,
    const float* __restrict__ W2, const float* __restrict__ Wa1,
    const float* __restrict__ Wa2,
    ushort* __restrict__ W2swz, ushort* __restrict__ f2swz,
    ushort* __restrict__ Wa1swz, ushort* __restrict__ Wa2swz,
    ushort* __restrict__ h1p, ushort* __restrict__ h2)
{
  int z = blockIdx.z;
  int t = threadIdx.x;
  __shared__ __align__(16) float As[32][33];
  __shared__ __align__(16) float Bs[32][64];

  if (z == 32) {
    // W2 -> B-fragment order [r][ks16][ct4][l64][j8]
    int sub = blockIdx.y * 4 + blockIdx.x;
    int r = sub >> 2, ks0 = (sub & 3) * 4;
    int ct = t >> 6, l = t & 63;
    #pragma unroll
    for (int ko = 0; ko < 4; ++ko) {
      int ks = ks0 + ko;
      uint4 pk;
      uint* pw = (uint*)&pk;
      #pragma unroll
      for (int jp = 0; jp < 4; ++jp) {
        int j0 = jp * 2;
        int d0 = ks * 16 + ((j0 >> 2) * 8) + ((l >> 5) * 4) + (j0 & 3);
        int d1 = ks * 16 + (((j0 + 1) >> 2) * 8) + ((l >> 5) * 4) + ((j0 + 1) & 3);
        int e = ct * 32 + (l & 31);
        pw[jp] = pack2(W2[(r * 256 + d0) * 128 + e], W2[(r * 256 + d1) * 128 + e]);
      }
      *(uint4*)&W2swz[(((r * 16 + ks) * 4 + ct) * 64 + l) * 8] = pk;
    }
    return;
  }
  if (z == 33) {
    // f2 -> B-fragment order [b][ks8][ctg8][l64][j8]
    int sub = blockIdx.y * 4 + blockIdx.x;
    int w = t >> 6, l = t & 63;
    #pragma unroll
    for (int ko = 0; ko < 4; ++ko) {
      int u = sub * 16 + w * 4 + ko;
      int b = u >> 6, ks = (u >> 3) & 7, ctg = u & 7;
      ushort us[8];
      #pragma unroll
      for (int j = 0; j < 8; ++j) {
        int k = ks * 16 + ((l >> 5) * 4) + (j & 3) + ((j >> 2) * 8);
        int n = ctg * 32 + (l & 31);
        us[j] = f2h(f2[((size_t)b * 128 + k) * 256 + n]);
      }
      uint4 pk;
      pk.x = (uint)us[0] | ((uint)us[1] << 16);
      pk.y = (uint)us[2] | ((uint)us[3] << 16);
      pk.z = (uint)us[4] | ((uint)us[5] << 16);
      pk.w = (uint)us[6] | ((uint)us[7] << 16);
      *(uint4*)&f2swz[(((b * 8 + ks) * 8 + ctg) * 64 + l) * 8] = pk;
    }
    return;
  }
  if (z == 34) {
    // Wa1[1024,512] -> [ks64][ct16][l64][j8]
    int sub = blockIdx.y * 4 + blockIdx.x;
    #pragma unroll
    for (int ko = 0; ko < 16; ++ko) {
      int id = sub * 4096 + ko * 256 + t;
      int ks = id >> 10, ct = (id >> 6) & 15, l = id & 63;
      ushort us[8];
      #pragma unroll
      for (int j = 0; j < 8; ++j) {
        int d = ks * 16 + ((l >> 5) * 4) + (j & 3) + ((j >> 2) * 8);
        int e = ct * 32 + (l & 31);
        us[j] = f2h(Wa1[(size_t)d * 512 + e]);
      }
      uint4 pk;
      pk.x = (uint)us[0] | ((uint)us[1] << 16);
      pk.y = (uint)us[2] | ((uint)us[3] << 16);
      pk.z = (uint)us[4] | ((uint)us[5] << 16);
      pk.w = (uint)us[6] | ((uint)us[7] << 16);
      *(uint4*)&Wa1swz[(size_t)id * 8] = pk;
    }
    return;
  }
  if (z == 35) {
    // Wa2[512,256] -> [ks32][ct8][l64][j8]
    int sub = blockIdx.y * 4 + blockIdx.x;
    #pragma unroll
    for (int ko = 0; ko < 4; ++ko) {
      int id = sub * 1024 + ko * 256 + t;
      int ks = id >> 9, ct = (id >> 6) & 7, l = id & 63;
      ushort us[8];
      #pragma unroll
      for (int j = 0; j < 8; ++j) {
        int d = ks * 16 + ((l >> 5) * 4) + (j & 3) + ((j >> 2) * 8);
        int e = ct * 32 + (l & 31);
        us[j] = f2h(Wa2[(size_t)d * 256 + e]);
      }
      uint4 pk;
      pk.x = (uint)us[0] | ((uint)us[1] << 16);
      pk.y = (uint)us[2] | ((uint)us[3] << 16);
      pk.z = (uint)us[4] | ((uint)us[5] << 16);
      pk.w = (uint)us[6] | ((uint)us[7] << 16);
      *(uint4*)&Wa2swz[(size_t)id * 8] = pk;
    }
    return;
  }

  int half = z >> 4, b = (z >> 2) & 3, r = z & 3;
  int rt = blockIdx.y, ct = blockIdx.x;
  int tm2 = t >> 4, tn4 = t & 15;
  int arow = t >> 3, akq = (t & 7) * 4;
  int bk = t >> 4, bn4 = (t & 15) * 4;

  const float* A = (half ? f2 : f1) + (size_t)b * 128 * 256;
  const float* W = W1 + (size_t)(r * 512 + half * 256) * 256;
  const float* Ab = A + (rt * 32 + arow) * 256;
  const float* Wb = W + ct * 64 + bn4;

  float4 pa = *(const float4*)&Ab[akq];
  float4 pb0 = *(const float4*)&Wb[bk * 256];
  float4 pb1 = *(const float4*)&Wb[(bk + 16) * 256];

  float acc[2][4];
  #pragma unroll
  for (int i = 0; i < 2; ++i)
    #pragma unroll
    for (int j = 0; j < 4; ++j) acc[i][j] = 0.f;

  for (int kc = 0; kc < 256; kc += 32) {
    __syncthreads();
    As[akq + 0][arow] = pa.x;
    As[akq + 1][arow] = pa.y;
    As[akq + 2][arow] = pa.z;
    As[akq + 3][arow] = pa.w;
    *(float4*)&Bs[bk][bn4] = pb0;
    *(float4*)&Bs[bk + 16][bn4] = pb1;
    __syncthreads();
    if (kc + 32 < 256) {
      pa  = *(const float4*)&Ab[kc + 32 + akq];
      pb0 = *(const float4*)&Wb[(kc + 32 + bk) * 256];
      pb1 = *(const float4*)&Wb[(kc + 32 + bk + 16) * 256];
    }
    #pragma unroll
    for (int kk = 0; kk < 32; ++kk) {
      float2 a = *(const float2*)&As[kk][tm2 * 2];
      float4 w = *(const float4*)&Bs[kk][tn4 * 4];
      acc[0][0] = fmaf(a.x, w.x, acc[0][0]); acc[0][1] = fmaf(a.x, w.y, acc[0][1]);
      acc[0][2] = fmaf(a.x, w.z, acc[0][2]); acc[0][3] = fmaf(a.x, w.w, acc[0][3]);
      acc[1][0] = fmaf(a.y, w.x, acc[1][0]); acc[1][1] = fmaf(a.y, w.y, acc[1][1]);
      acc[1][2] = fmaf(a.y, w.z, acc[1][2]); acc[1][3] = fmaf(a.y, w.w, acc[1][3]);
    }
  }

  int col = ct * 64 + tn4 * 4;
  float4 bv;
  if (half) { bv.x = bv.y = bv.z = bv.w = 0.f; }
  else      { bv = *(const float4*)&b1[r * 256 + col]; }
  uint* hu = (uint*)(half ? h2 : h1p);
  #pragma unroll
  for (int qm = 0; qm < 2; ++qm) {
    int row = rt * 32 + tm2 * 2 + qm;
    uint2 pv;
    pv.x = pack2(acc[qm][0] + bv.x, acc[qm][1] + bv.y);
    pv.y = pack2(acc[qm][2] + bv.z, acc[qm][3] + bv.w);
    *(uint2*)&hu[((size_t)((b * 4 + r) * 128 + row)) * 128 + (col >> 1)] = pv;
  }
}

// ---------------- fp16 MFMA scores: 2x2 micro-tile per wave ----------------
__global__ __launch_bounds__(256, 4) void k_scores_mfma(
    const ushort* __restrict__ h1p, const ushort* __restrict__ h2,
    const ushort* __restrict__ W2swz, const float* __restrict__ b2,
    const float* __restrict__ w3, const float* __restrict__ b3,
    float* __restrict__ scores)
{
  int bid = blockIdx.x;        // 2048: b(4) x r(4) x it(16) x jt(8)
  int jt = bid & 7;
  int it = (bid >> 3) & 15;
  int r  = (bid >> 7) & 3;
  int b  = bid >> 9;
  int t = threadIdx.x, w = t >> 6, l = t & 63;
  __shared__ uint h1u[8][132];
  __shared__ uint h2u[16][132];
  __shared__ float xch[4][2][2][16];

  const uint* h1g = (const uint*)h1p + ((size_t)((b * 4 + r) * 128 + it * 8)) * 128;
  const uint* h2g = (const uint*)h2  + ((size_t)((b * 4 + r) * 128 + jt * 16)) * 128;
  {
    int row = t >> 5, c4 = (t & 31) * 4;
    *(uint4*)&h1u[row][c4] = *(const uint4*)&h1g[row * 128 + c4];
    *(uint4*)&h2u[row][c4] = *(const uint4*)&h2g[row * 128 + c4];
    *(uint4*)&h2u[row + 8][c4] = *(const uint4*)&h2g[(row + 8) * 128 + c4];
  }

  f32x16 acc[2][2];
  #pragma unroll
  for (int i = 0; i < 2; ++i)
    #pragma unroll
    for (int c = 0; c < 2; ++c)
      #pragma unroll
      for (int e = 0; e < 16; ++e) acc[i][c][e] = 0.f;

  int rtp = w & 1, ctp = w >> 1;
  int hi2 = (l >> 5) * 2;
  int m31 = l & 31;
  int jrow = m31 & 15;
  int irow0 = (rtp * 2 + 0) * 2 + (m31 >> 4);
  int irow1 = (rtp * 2 + 1) * 2 + (m31 >> 4);
  const ushort* bptr = W2swz + r * (16 * 4 * 64 * 8);

  __syncthreads();

  const uint* h1r0 = &h1u[irow0][0];
  const uint* h1r1 = &h1u[irow1][0];
  const uint* h2r  = &h2u[jrow][0];
  for (int ks = 0; ks < 16; ++ks) {
    int u0 = ks * 8 + hi2;
    uint2 ya  = *(const uint2*)&h2r[u0];
    uint2 yb  = *(const uint2*)&h2r[u0 + 4];
    uint2 xa0 = *(const uint2*)&h1r0[u0];
    uint2 xb0 = *(const uint2*)&h1r0[u0 + 4];
    uint2 xa1 = *(const uint2*)&h1r1[u0];
    uint2 xb1 = *(const uint2*)&h1r1[u0 + 4];
    uint4 pk0, pk1;
    pk0.x = pk_relu(pk_add(xa0.x, ya.x));
    pk0.y = pk_relu(pk_add(xa0.y, ya.y));
    pk0.z = pk_relu(pk_add(xb0.x, yb.x));
    pk0.w = pk_relu(pk_add(xb0.y, yb.y));
    pk1.x = pk_relu(pk_add(xa1.x, ya.x));
    pk1.y = pk_relu(pk_add(xa1.y, ya.y));
    pk1.z = pk_relu(pk_add(xb1.x, yb.x));
    pk1.w = pk_relu(pk_add(xb1.y, yb.y));
    f16x8 af0 = __builtin_bit_cast(f16x8, pk0);
    f16x8 af1 = __builtin_bit_cast(f16x8, pk1);
    uint4 braw0 = *(const uint4*)&bptr[((ks * 4 + ctp * 2 + 0) * 64 + l) * 8];
    uint4 braw1 = *(const uint4*)&bptr[((ks * 4 + ctp * 2 + 1) * 64 + l) * 8];
    f16x8 bf0 = __builtin_bit_cast(f16x8, braw0);
    f16x8 bf1 = __builtin_bit_cast(f16x8, braw1);
    acc[0][0] = __builtin_amdgcn_mfma_f32_32x32x16_f16(af0, bf0, acc[0][0], 0, 0, 0);
    acc[0][1] = __builtin_amdgcn_mfma_f32_32x32x16_f16(af0, bf1, acc[0][1], 0, 0, 0);
    acc[1][0] = __builtin_amdgcn_mfma_f32_32x32x16_f16(af1, bf0, acc[1][0], 0, 0, 0);
    acc[1][1] = __builtin_amdgcn_mfma_f32_32x32x16_f16(af1, bf1, acc[1][1], 0, 0, 0);
  }

  float sp[2][16];
  #pragma unroll
  for (int i = 0; i < 2; ++i)
    #pragma unroll
    for (int g = 0; g < 16; ++g) sp[i][g] = 0.f;
  #pragma unroll
  for (int ctl = 0; ctl < 2; ++ctl) {
    int e = (ctp * 2 + ctl) * 32 + m31;
    float w3v = w3[r * 128 + e];
    float b2v = b2[r * 128 + e];
    #pragma unroll
    for (int i = 0; i < 2; ++i)
      #pragma unroll
      for (int g = 0; g < 16; ++g)
        sp[i][g] = fmaf(w3v, fmaxf(acc[i][ctl][g] + b2v, 0.f), sp[i][g]);
  }
  #pragma unroll
  for (int off = 16; off >= 1; off >>= 1)
    #pragma unroll
    for (int i = 0; i < 2; ++i)
      #pragma unroll
      for (int g = 0; g < 16; ++g)
        sp[i][g] += __shfl_xor(sp[i][g], off, 64);
  int hi = l >> 5;
  if (m31 == 0) {
    #pragma unroll
    for (int i = 0; i < 2; ++i)
      #pragma unroll
      for (int g = 0; g < 16; ++g)
        xch[w][i][hi][g] = sp[i][g];
  }
  __syncthreads();
  if (w < 2 && m31 == 0) {
    float b3v = b3[r];
    float* sc_base = scores + (((b * 4 + r) * 128 + it * 8) * 128) + jt * 16;
    #pragma unroll
    for (int i = 0; i < 2; ++i)
      #pragma unroll
      for (int g = 0; g < 16; ++g) {
        float s = xch[w][i][hi][g] + xch[w + 2][i][hi][g] + b3v;
        int p = (w * 2 + i) * 32 + (g & 3) + 8 * (g >> 2) + hi * 4;
        sc_base[(p >> 4) * 128 + (p & 15)] = s;
      }
  }
}

// ---------------- softmax + rel; writes all_rel packed fp16 row-major ----------------
__global__ __launch_bounds__(64, 1) void k_softrel_mfma(
    const float* __restrict__ scores, const ushort* __restrict__ f2swz,
    ushort* __restrict__ all_rel_h)
{
  int bid = blockIdx.x;         // 128: b(4) x r(4) x nh(2) x rowq(4)
  int rowq = bid & 3;
  int nh = (bid >> 2) & 1;
  int r  = (bid >> 3) & 3;
  int b  = bid >> 5;
  int l = threadIdx.x;
  int row = rowq * 32 + (l & 31);
  const float* srow = scores + ((size_t)(b * 4 + r) * 128 + row) * 128;

  float p[128];
  #pragma unroll
  for (int q = 0; q < 32; ++q) {
    float4 v = *(const float4*)&srow[q * 4];
    p[q * 4 + 0] = v.x; p[q * 4 + 1] = v.y;
    p[q * 4 + 2] = v.z; p[q * 4 + 3] = v.w;
  }
  float m = p[0];
  #pragma unroll
  for (int j = 1; j < 128; ++j) m = fmaxf(m, p[j]);
  float sum = 0.f;
  #pragma unroll
  for (int j = 0; j < 128; ++j) { p[j] = __expf(p[j] - m); sum += p[j]; }
  float inv = 1.f / sum;
  uint preg[64];
  #pragma unroll
  for (int q = 0; q < 64; ++q)
    preg[q] = pack2(p[2 * q] * inv, p[2 * q + 1] * inv);

  f32x16 acc[4];
  #pragma unroll
  for (int c = 0; c < 4; ++c)
    #pragma unroll
    for (int e = 0; e < 16; ++e) acc[c][e] = 0.f;

  int hi2 = (l >> 5) * 2;
  const ushort* bbase = f2swz + (size_t)b * (8 * 8 * 64 * 8);
  #pragma unroll
  for (int ks = 0; ks < 8; ++ks) {
    int b2i = ks * 8 + hi2;
    uint4 pk = make_uint4(preg[b2i], preg[b2i + 1], preg[b2i + 4], preg[b2i + 5]);
    f16x8 af = __builtin_bit_cast(f16x8, pk);
    #pragma unroll
    for (int ct = 0; ct < 4; ++ct) {
      uint4 braw = *(const uint4*)&bbase[((ks * 8 + nh * 4 + ct) * 64 + l) * 8];
      f16x8 bfr = __builtin_bit_cast(f16x8, braw);
      acc[ct] = __builtin_amdgcn_mfma_f32_32x32x16_f16(af, bfr, acc[ct], 0, 0, 0);
    }
  }

  ushort* dst = all_rel_h + (size_t)(b * 128) * 1024;
  int ebase = r * 256 + nh * 128 + (l & 31);
  int half4 = (l >> 5) << 2;
  #pragma unroll
  for (int ct = 0; ct < 4; ++ct)
    #pragma unroll
    for (int g = 0; g < 16; ++g) {
      int i = rowq * 32 + (g & 3) + 8 * (g >> 2) + half4;
      dst[(size_t)i * 1024 + ebase + ct * 32] = f2h(acc[ct][g]);
    }
}

// ---------------- fused MLP: out = relu(A@Wa1+ba1)@Wa2+ba2, all fp16 MFMA ----------------
// 16 blocks x 512 thr (8 waves). Block owns 32 rows. Phase1: hidden(32x512) -> LDS fp16.
__global__ __launch_bounds__(512) void k_mlp(
    const ushort* __restrict__ all_rel_h, const ushort* __restrict__ Wa1swz,
    const float* __restrict__ ba1, const ushort* __restrict__ Wa2swz,
    const float* __restrict__ ba2, float* __restrict__ out)
{
  int b0 = blockIdx.x;
  int t = threadIdx.x, w = t >> 6, l = t & 63;
  __shared__ uint Ah[32][514];    // 32 rows x 512 uints (1024 halves), pad 514 (2-way ok)
  __shared__ uint Hh[32][258];    // hidden fp16: 32 x 256 uints, pad 258

  const uint* Ag = (const uint*)all_rel_h + (size_t)b0 * 32 * 512;
  #pragma unroll
  for (int it = 0; it < 8; ++it) {
    int idx = it * 512 + t;            // 4096 = 32 rows x 128 uint2-groups? (uint2 staging)
    int row = idx >> 7, c2 = (idx & 127) * 4;
    uint2 v0 = *(const uint2*)&Ag[row * 512 + c2];
    uint2 v1 = *(const uint2*)&Ag[row * 512 + c2 + 2];
    *(uint2*)&Ah[row][c2] = v0;
    *(uint2*)&Ah[row][c2 + 2] = v1;
  }
  __syncthreads();

  int m31 = l & 31, hi = l >> 5, hi2 = hi * 2;

  // Phase 1: hidden cols [w*64, +64)
  f32x16 acc0, acc1;
  #pragma unroll
  for (int e = 0; e < 16; ++e) { acc0[e] = 0.f; acc1[e] = 0.f; }
  for (int ks = 0; ks < 64; ++ks) {
    int u0 = ks * 8 + hi2;
    uint2 xa = *(const uint2*)&Ah[m31][u0];
    uint2 xb = *(const uint2*)&Ah[m31][u0 + 4];
    uint4 a4 = make_uint4(xa.x, xa.y, xb.x, xb.y);
    f16x8 af = __builtin_bit_cast(f16x8, a4);
    uint4 braw0 = *(const uint4*)&Wa1swz[(size_t)(((ks * 16 + w * 2 + 0) * 64 + l)) * 8];
    uint4 braw1 = *(const uint4*)&Wa1swz[(size_t)(((ks * 16 + w * 2 + 1) * 64 + l)) * 8];
    f16x8 bf0 = __builtin_bit_cast(f16x8, braw0);
    f16x8 bf1 = __builtin_bit_cast(f16x8, braw1);
    acc0 = __builtin_amdgcn_mfma_f32_32x32x16_f16(af, bf0, acc0, 0, 0, 0);
    acc1 = __builtin_amdgcn_mfma_f32_32x32x16_f16(af, bf1, acc1, 0, 0, 0);
  }
  ushort* Hs = (ushort*)Hh;
  #pragma unroll
  for (int ctl = 0; ctl < 2; ++ctl) {
    int e = (w * 2 + ctl) * 32 + m31;
    float bv = ba1[e];
    #pragma unroll
    for (int g = 0; g < 16; ++g) {
      int row = (g & 3) + 8 * (g >> 2) + 4 * hi;
      float v = fmaxf((ctl ? acc1[g] : acc0[g]) + bv, 0.f);
      Hs[row * 516 + e] = f2h(v);
    }
  }
  __syncthreads();

  // Phase 2: out cols [w*32, +32), K=512
  f32x16 acc2;
  #pragma unroll
  for (int e = 0; e < 16; ++e) acc2[e] = 0.f;
  for (int ks = 0; ks < 32; ++ks) {
    int u0 = ks * 8 + hi2;
    uint2 xa = *(const uint2*)&Hh[m31][u0];
    uint2 xb = *(const uint2*)&Hh[m31][u0 + 4];
    uint4 a4 = make_uint4(xa.x, xa.y, xb.x, xb.y);
    f16x8 af = __builtin_bit_cast(f16x8, a4);
    uint4 braw = *(const uint4*)&Wa2swz[(size_t)(((ks * 8 + w) * 64 + l)) * 8];
    f16x8 bfr = __builtin_bit_cast(f16x8, braw);
    acc2 = __builtin_amdgcn_mfma_f32_32x32x16_f16(af, bfr, acc2, 0, 0, 0);
  }
  float bv2 = ba2[w * 32 + m31];
  #pragma unroll
  for (int g = 0; g < 16; ++g) {
    int row = (g & 3) + 8 * (g >> 2) + 4 * hi;
    out[(size_t)(b0 * 32 + row) * 256 + w * 32 + m31] = acc2[g] + bv2;
  }
}

extern "C" void kernel_launch(void* const* d_in, const int* in_sizes, int n_in,
                              void* d_out, int out_size, void* d_ws, size_t ws_size,
                              hipStream_t stream) {
  const float* f1  = (const float*)d_in[0];
  const float* f2  = (const float*)d_in[1];
  const float* W1  = (const float*)d_in[2];
  const float* b1  = (const float*)d_in[3];
  const float* W2  = (const float*)d_in[4];
  const float* b2  = (const float*)d_in[5];
  const float* w3  = (const float*)d_in[6];
  const float* b3  = (const float*)d_in[7];
  const float* Wa1 = (const float*)d_in[8];
  const float* ba1 = (const float*)d_in[9];
  const float* Wa2 = (const float*)d_in[10];
  const float* ba2 = (const float*)d_in[11];
  float* out = (float*)d_out;
  float* ws = (float*)d_ws;

  // Workspace (float offsets):
  ushort* h1p      = (ushort*)ws;                 // @0MB,   1MB
  ushort* h2       = (ushort*)(ws + 262144);      // @1MB,   1MB
  float*  scores   = ws + 524288;                 // @2MB,   1MB
  ushort* all_relh = (ushort*)(ws + 786432);      // @3MB,   1MB (512x1024 fp16)
  ushort* W2swz    = (ushort*)(ws + 1048576);     // @4MB,   256KB
  ushort* f2swz    = (ushort*)(ws + 1114112);     // @4.25MB,256KB
  ushort* Wa1swz   = (ushort*)(ws + 1179648);     // @4.5MB, 1MB
  ushort* Wa2swz   = (ushort*)(ws + 1441792);     // @5.5MB, 256KB

  hipLaunchKernelGGL(k_proj_w2, dim3(4, 4, 36), dim3(256), 0, stream,
                     f1, f2, W1, b1, W2, Wa1, Wa2,
                     W2swz, f2swz, Wa1swz, Wa2swz, h1p, h2);
  hipLaunchKernelGGL(k_scores_mfma, dim3(2048), dim3(256), 0, stream,
                     h1p, h2, W2swz, b2, w3, b3, scores);
  hipLaunchKernelGGL(k_softrel_mfma, dim3(128), dim3(64), 0, stream,
                     scores, f2swz, all_relh);
  hipLaunchKernelGGL(k_mlp, dim3(16), dim3(512), 0, stream,
                     all_relh, Wa1swz, ba1, Wa2swz, ba2, out);
}

// Round 11
// 64.583 us; speedup vs baseline: 1.2300x; 1.2300x over previous
//
#include <hip/hip_runtime.h>

// Shapes: B=4, N1=N2=128, D=256, R=4, E=D/2=128
// Pipeline (6 dispatches, everything matmul-shaped on fp16 MFMA):
//   1 k_prep      : cast f1/f2 -> fp16; swizzle W1/W2/f2/Wa1/Wa2 into B-fragment order
//   2 k_proj_mfma : h1p/h2 = f@W1(+b1), fp16 MFMA, packed fp16 out
//   3 k_scores    : scores via fp16 MFMA, 2x2 micro-tile per wave
//   4 k_softrel   : softmax + rel via fp16 MFMA -> all_rel packed fp16
//   5 k_mlp1      : hidden = relu(all_rel@Wa1+ba1), fp16 MFMA, fp16 out
//   6 k_mlp2      : out = hidden@Wa2+ba2, fp16 MFMA, fp32 out

typedef _Float16 f16x8 __attribute__((ext_vector_type(8)));
typedef float f32x16 __attribute__((ext_vector_type(16)));

static __device__ __forceinline__ ushort to_h(float f) {
  _Float16 h = (_Float16)f;
  return __builtin_bit_cast(ushort, h);
}
static __device__ __forceinline__ uint pack2(float a, float b) {
  return (uint)to_h(a) | ((uint)to_h(b) << 16);
}
static __device__ __forceinline__ uint pk_add(uint a, uint b) {
  uint r;
  asm("v_pk_add_f16 %0, %1, %2" : "=v"(r) : "v"(a), "v"(b));
  return r;
}
static __device__ __forceinline__ uint pk_relu(uint a) {
  uint r;
  asm("v_pk_max_f16 %0, %1, %2" : "=v"(r) : "v"(a), "v"(0u));
  return r;
}

// ---------------- prep: casts + all fragment swizzles (flat grid of 320) ----------------
__global__ __launch_bounds__(256) void k_prep(
    const float* __restrict__ f1, const float* __restrict__ f2,
    const float* __restrict__ W1, const float* __restrict__ W2,
    const float* __restrict__ Wa1, const float* __restrict__ Wa2,
    uint* __restrict__ f1hp, uint* __restrict__ f2hp,
    ushort* __restrict__ W1swz, ushort* __restrict__ W2swz,
    ushort* __restrict__ f2swz, ushort* __restrict__ Wa1swz,
    ushort* __restrict__ Wa2swz)
{
  int blk = blockIdx.x, t = threadIdx.x;
  if (blk < 128) {
    // f1/f2 -> packed fp16 rows
    int u = blk * 256 + t;                 // [0, 32768)
    float4 a = *(const float4*)&f1[u * 4];
    float4 b = *(const float4*)&f2[u * 4];
    *(uint2*)&f1hp[u * 2] = make_uint2(pack2(a.x, a.y), pack2(a.z, a.w));
    *(uint2*)&f2hp[u * 2] = make_uint2(pack2(b.x, b.y), pack2(b.z, b.w));
    return;
  }
  if (blk < 256) {
    // W1 -> B-frag order [r][half][ks16][ct8][l64][j8]
    int unit = blk - 128;
    int r = unit >> 5, half = (unit >> 4) & 1, ks = unit & 15;
    int l = t & 63, ctq = t >> 6;
    #pragma unroll
    for (int ci = 0; ci < 2; ++ci) {
      int ct = ctq + ci * 4;
      int e = ct * 32 + (l & 31);
      ushort us[8];
      #pragma unroll
      for (int j = 0; j < 8; ++j) {
        int d = ks * 16 + ((l >> 5) * 4) + (j & 3) + ((j >> 2) * 8);
        us[j] = to_h(W1[(size_t)(r * 512 + half * 256 + d) * 256 + e]);
      }
      uint4 pk;
      pk.x = (uint)us[0] | ((uint)us[1] << 16);
      pk.y = (uint)us[2] | ((uint)us[3] << 16);
      pk.z = (uint)us[4] | ((uint)us[5] << 16);
      pk.w = (uint)us[6] | ((uint)us[7] << 16);
      *(uint4*)&W1swz[(size_t)((((r * 2 + half) * 16 + ks) * 8 + ct) * 64 + l) * 8] = pk;
    }
    return;
  }
  if (blk < 272) {
    // W2 -> [r][ks16][ct4][l64][j8]
    int sub = blk - 256;
    int r = sub >> 2, ks0 = (sub & 3) * 4;
    int ct = t >> 6, l = t & 63;
    #pragma unroll
    for (int ko = 0; ko < 4; ++ko) {
      int ks = ks0 + ko;
      ushort us[8];
      #pragma unroll
      for (int j = 0; j < 8; ++j) {
        int d = ks * 16 + ((j >> 2) * 8) + ((l >> 5) * 4) + (j & 3);
        int e = ct * 32 + (l & 31);
        us[j] = to_h(W2[(r * 256 + d) * 128 + e]);
      }
      uint4 pk;
      pk.x = (uint)us[0] | ((uint)us[1] << 16);
      pk.y = (uint)us[2] | ((uint)us[3] << 16);
      pk.z = (uint)us[4] | ((uint)us[5] << 16);
      pk.w = (uint)us[6] | ((uint)us[7] << 16);
      *(uint4*)&W2swz[(((r * 16 + ks) * 4 + ct) * 64 + l) * 8] = pk;
    }
    return;
  }
  if (blk < 288) {
    // f2 -> [b][ks8][ctg8][l64][j8]
    int sub = blk - 272;
    int w = t >> 6, l = t & 63;
    #pragma unroll
    for (int ko = 0; ko < 4; ++ko) {
      int u = sub * 16 + w * 4 + ko;
      int b = u >> 6, ks = (u >> 3) & 7, ctg = u & 7;
      ushort us[8];
      #pragma unroll
      for (int j = 0; j < 8; ++j) {
        int k = ks * 16 + ((l >> 5) * 4) + (j & 3) + ((j >> 2) * 8);
        int n = ctg * 32 + (l & 31);
        us[j] = to_h(f2[((size_t)b * 128 + k) * 256 + n]);
      }
      uint4 pk;
      pk.x = (uint)us[0] | ((uint)us[1] << 16);
      pk.y = (uint)us[2] | ((uint)us[3] << 16);
      pk.z = (uint)us[4] | ((uint)us[5] << 16);
      pk.w = (uint)us[6] | ((uint)us[7] << 16);
      *(uint4*)&f2swz[(((b * 8 + ks) * 8 + ctg) * 64 + l) * 8] = pk;
    }
    return;
  }
  if (blk < 304) {
    // Wa1[1024,512] -> [ks64][ct16][l64][j8]
    int sub = blk - 288;
    #pragma unroll
    for (int ko = 0; ko < 16; ++ko) {
      int id = sub * 4096 + ko * 256 + t;
      int ks = id >> 10, ct = (id >> 6) & 15, l = id & 63;
      ushort us[8];
      #pragma unroll
      for (int j = 0; j < 8; ++j) {
        int d = ks * 16 + ((l >> 5) * 4) + (j & 3) + ((j >> 2) * 8);
        int e = ct * 32 + (l & 31);
        us[j] = to_h(Wa1[(size_t)d * 512 + e]);
      }
      uint4 pk;
      pk.x = (uint)us[0] | ((uint)us[1] << 16);
      pk.y = (uint)us[2] | ((uint)us[3] << 16);
      pk.z = (uint)us[4] | ((uint)us[5] << 16);
      pk.w = (uint)us[6] | ((uint)us[7] << 16);
      *(uint4*)&Wa1swz[(size_t)id * 8] = pk;
    }
    return;
  }
  {
    // Wa2[512,256] -> [ks32][ct8][l64][j8]
    int sub = blk - 304;
    #pragma unroll
    for (int ko = 0; ko < 4; ++ko) {
      int id = sub * 1024 + ko * 256 + t;
      int ks = id >> 9, ct = (id >> 6) & 7, l = id & 63;
      ushort us[8];
      #pragma unroll
      for (int j = 0; j < 8; ++j) {
        int d = ks * 16 + ((l >> 5) * 4) + (j & 3) + ((j >> 2) * 8);
        int e = ct * 32 + (l & 31);
        us[j] = to_h(Wa2[(size_t)d * 256 + e]);
      }
      uint4 pk;
      pk.x = (uint)us[0] | ((uint)us[1] << 16);
      pk.y = (uint)us[2] | ((uint)us[3] << 16);
      pk.z = (uint)us[4] | ((uint)us[5] << 16);
      pk.w = (uint)us[6] | ((uint)us[7] << 16);
      *(uint4*)&Wa2swz[(size_t)id * 8] = pk;
    }
    return;
  }
}

// ---------------- projection via fp16 MFMA ----------------
// 128 blocks: b(4) x r(4) x half(2) x it(4); 4 waves; wave w -> e-cols [w*64,+64).
__global__ __launch_bounds__(256) void k_proj_mfma(
    const uint* __restrict__ f1hp, const uint* __restrict__ f2hp,
    const ushort* __restrict__ W1swz, const float* __restrict__ b1,
    ushort* __restrict__ h1p, ushort* __restrict__ h2)
{
  int bid = blockIdx.x;
  int it = bid & 3;
  int half = (bid >> 2) & 1;
  int r = (bid >> 3) & 3;
  int b = bid >> 5;
  int t = threadIdx.x, w = t >> 6, l = t & 63;
  __shared__ uint Au[32][132];

  const uint* src = (half ? f2hp : f1hp) + (size_t)b * 16384 + it * 32 * 128;
  #pragma unroll
  for (int q = 0; q < 4; ++q) {
    int lin = q * 256 + t;
    int row = lin >> 5, c4 = (lin & 31) * 4;
    *(uint4*)&Au[row][c4] = *(const uint4*)&src[row * 128 + c4];
  }
  __syncthreads();

  int m31 = l & 31, hi = l >> 5, hi2 = hi * 2;
  f32x16 acc0, acc1;
  #pragma unroll
  for (int e = 0; e < 16; ++e) { acc0[e] = 0.f; acc1[e] = 0.f; }

  const ushort* bb = W1swz + (size_t)(r * 2 + half) * 65536;
  for (int ks = 0; ks < 16; ++ks) {
    int u0 = ks * 8 + hi2;
    uint2 xa = *(const uint2*)&Au[m31][u0];
    uint2 xb = *(const uint2*)&Au[m31][u0 + 4];
    uint4 a4 = make_uint4(xa.x, xa.y, xb.x, xb.y);
    f16x8 af = __builtin_bit_cast(f16x8, a4);
    uint4 br0 = *(const uint4*)&bb[((ks * 8 + w * 2 + 0) * 64 + l) * 8];
    uint4 br1 = *(const uint4*)&bb[((ks * 8 + w * 2 + 1) * 64 + l) * 8];
    f16x8 bf0 = __builtin_bit_cast(f16x8, br0);
    f16x8 bf1 = __builtin_bit_cast(f16x8, br1);
    acc0 = __builtin_amdgcn_mfma_f32_32x32x16_f16(af, bf0, acc0, 0, 0, 0);
    acc1 = __builtin_amdgcn_mfma_f32_32x32x16_f16(af, bf1, acc1, 0, 0, 0);
  }

  ushort* ho = (half ? h2 : h1p) + ((size_t)((b * 4 + r) * 128 + it * 32)) * 256;
  #pragma unroll
  for (int ctl = 0; ctl < 2; ++ctl) {
    int e = (w * 2 + ctl) * 32 + m31;
    float bv = half ? 0.f : b1[r * 256 + e];
    #pragma unroll
    for (int g = 0; g < 16; ++g) {
      int row = (g & 3) + 8 * (g >> 2) + 4 * hi;
      ho[row * 256 + e] = to_h((ctl ? acc1[g] : acc0[g]) + bv);
    }
  }
}

// ---------------- fp16 MFMA scores: 2x2 micro-tile per wave ----------------
__global__ __launch_bounds__(256, 4) void k_scores_mfma(
    const ushort* __restrict__ h1p, const ushort* __restrict__ h2,
    const ushort* __restrict__ W2swz, const float* __restrict__ b2,
    const float* __restrict__ w3, const float* __restrict__ b3,
    float* __restrict__ scores)
{
  int bid = blockIdx.x;        // 2048: b(4) x r(4) x it(16) x jt(8)
  int jt = bid & 7;
  int it = (bid >> 3) & 15;
  int r  = (bid >> 7) & 3;
  int b  = bid >> 9;
  int t = threadIdx.x, w = t >> 6, l = t & 63;
  __shared__ uint h1u[8][132];
  __shared__ uint h2u[16][132];
  __shared__ float xch[4][2][2][16];

  const uint* h1g = (const uint*)h1p + ((size_t)((b * 4 + r) * 128 + it * 8)) * 128;
  const uint* h2g = (const uint*)h2  + ((size_t)((b * 4 + r) * 128 + jt * 16)) * 128;
  {
    int row = t >> 5, c4 = (t & 31) * 4;
    *(uint4*)&h1u[row][c4] = *(const uint4*)&h1g[row * 128 + c4];
    *(uint4*)&h2u[row][c4] = *(const uint4*)&h2g[row * 128 + c4];
    *(uint4*)&h2u[row + 8][c4] = *(const uint4*)&h2g[(row + 8) * 128 + c4];
  }

  f32x16 acc[2][2];
  #pragma unroll
  for (int i = 0; i < 2; ++i)
    #pragma unroll
    for (int c = 0; c < 2; ++c)
      #pragma unroll
      for (int e = 0; e < 16; ++e) acc[i][c][e] = 0.f;

  int rtp = w & 1, ctp = w >> 1;
  int hi2 = (l >> 5) * 2;
  int m31 = l & 31;
  int jrow = m31 & 15;
  int irow0 = (rtp * 2 + 0) * 2 + (m31 >> 4);
  int irow1 = (rtp * 2 + 1) * 2 + (m31 >> 4);
  const ushort* bptr = W2swz + r * (16 * 4 * 64 * 8);

  __syncthreads();

  const uint* h1r0 = &h1u[irow0][0];
  const uint* h1r1 = &h1u[irow1][0];
  const uint* h2r  = &h2u[jrow][0];
  for (int ks = 0; ks < 16; ++ks) {
    int u0 = ks * 8 + hi2;
    uint2 ya  = *(const uint2*)&h2r[u0];
    uint2 yb  = *(const uint2*)&h2r[u0 + 4];
    uint2 xa0 = *(const uint2*)&h1r0[u0];
    uint2 xb0 = *(const uint2*)&h1r0[u0 + 4];
    uint2 xa1 = *(const uint2*)&h1r1[u0];
    uint2 xb1 = *(const uint2*)&h1r1[u0 + 4];
    uint4 pk0, pk1;
    pk0.x = pk_relu(pk_add(xa0.x, ya.x));
    pk0.y = pk_relu(pk_add(xa0.y, ya.y));
    pk0.z = pk_relu(pk_add(xb0.x, yb.x));
    pk0.w = pk_relu(pk_add(xb0.y, yb.y));
    pk1.x = pk_relu(pk_add(xa1.x, ya.x));
    pk1.y = pk_relu(pk_add(xa1.y, ya.y));
    pk1.z = pk_relu(pk_add(xb1.x, yb.x));
    pk1.w = pk_relu(pk_add(xb1.y, yb.y));
    f16x8 af0 = __builtin_bit_cast(f16x8, pk0);
    f16x8 af1 = __builtin_bit_cast(f16x8, pk1);
    uint4 braw0 = *(const uint4*)&bptr[((ks * 4 + ctp * 2 + 0) * 64 + l) * 8];
    uint4 braw1 = *(const uint4*)&bptr[((ks * 4 + ctp * 2 + 1) * 64 + l) * 8];
    f16x8 bf0 = __builtin_bit_cast(f16x8, braw0);
    f16x8 bf1 = __builtin_bit_cast(f16x8, braw1);
    acc[0][0] = __builtin_amdgcn_mfma_f32_32x32x16_f16(af0, bf0, acc[0][0], 0, 0, 0);
    acc[0][1] = __builtin_amdgcn_mfma_f32_32x32x16_f16(af0, bf1, acc[0][1], 0, 0, 0);
    acc[1][0] = __builtin_amdgcn_mfma_f32_32x32x16_f16(af1, bf0, acc[1][0], 0, 0, 0);
    acc[1][1] = __builtin_amdgcn_mfma_f32_32x32x16_f16(af1, bf1, acc[1][1], 0, 0, 0);
  }

  float sp[2][16];
  #pragma unroll
  for (int i = 0; i < 2; ++i)
    #pragma unroll
    for (int g = 0; g < 16; ++g) sp[i][g] = 0.f;
  #pragma unroll
  for (int ctl = 0; ctl < 2; ++ctl) {
    int e = (ctp * 2 + ctl) * 32 + m31;
    float w3v = w3[r * 128 + e];
    float b2v = b2[r * 128 + e];
    #pragma unroll
    for (int i = 0; i < 2; ++i)
      #pragma unroll
      for (int g = 0; g < 16; ++g)
        sp[i][g] = fmaf(w3v, fmaxf(acc[i][ctl][g] + b2v, 0.f), sp[i][g]);
  }
  #pragma unroll
  for (int off = 16; off >= 1; off >>= 1)
    #pragma unroll
    for (int i = 0; i < 2; ++i)
      #pragma unroll
      for (int g = 0; g < 16; ++g)
        sp[i][g] += __shfl_xor(sp[i][g], off, 64);
  int hi = l >> 5;
  if (m31 == 0) {
    #pragma unroll
    for (int i = 0; i < 2; ++i)
      #pragma unroll
      for (int g = 0; g < 16; ++g)
        xch[w][i][hi][g] = sp[i][g];
  }
  __syncthreads();
  if (w < 2 && m31 == 0) {
    float b3v = b3[r];
    float* sc_base = scores + (((b * 4 + r) * 128 + it * 8) * 128) + jt * 16;
    #pragma unroll
    for (int i = 0; i < 2; ++i)
      #pragma unroll
      for (int g = 0; g < 16; ++g) {
        float s = xch[w][i][hi][g] + xch[w + 2][i][hi][g] + b3v;
        int p = (w * 2 + i) * 32 + (g & 3) + 8 * (g >> 2) + hi * 4;
        sc_base[(p >> 4) * 128 + (p & 15)] = s;
      }
  }
}

// ---------------- softmax + rel; writes all_rel packed fp16 row-major ----------------
__global__ __launch_bounds__(64, 1) void k_softrel_mfma(
    const float* __restrict__ scores, const ushort* __restrict__ f2swz,
    ushort* __restrict__ all_rel_h)
{
  int bid = blockIdx.x;         // 128: b(4) x r(4) x nh(2) x rowq(4)
  int rowq = bid & 3;
  int nh = (bid >> 2) & 1;
  int r  = (bid >> 3) & 3;
  int b  = bid >> 5;
  int l = threadIdx.x;
  int row = rowq * 32 + (l & 31);
  const float* srow = scores + ((size_t)(b * 4 + r) * 128 + row) * 128;

  float p[128];
  #pragma unroll
  for (int q = 0; q < 32; ++q) {
    float4 v = *(const float4*)&srow[q * 4];
    p[q * 4 + 0] = v.x; p[q * 4 + 1] = v.y;
    p[q * 4 + 2] = v.z; p[q * 4 + 3] = v.w;
  }
  float m = p[0];
  #pragma unroll
  for (int j = 1; j < 128; ++j) m = fmaxf(m, p[j]);
  float sum = 0.f;
  #pragma unroll
  for (int j = 0; j < 128; ++j) { p[j] = __expf(p[j] - m); sum += p[j]; }
  float inv = 1.f / sum;
  uint preg[64];
  #pragma unroll
  for (int q = 0; q < 64; ++q)
    preg[q] = pack2(p[2 * q] * inv, p[2 * q + 1] * inv);

  f32x16 acc[4];
  #pragma unroll
  for (int c = 0; c < 4; ++c)
    #pragma unroll
    for (int e = 0; e < 16; ++e) acc[c][e] = 0.f;

  int hi2 = (l >> 5) * 2;
  const ushort* bbase = f2swz + (size_t)b * (8 * 8 * 64 * 8);
  #pragma unroll
  for (int ks = 0; ks < 8; ++ks) {
    int b2i = ks * 8 + hi2;
    uint4 pk = make_uint4(preg[b2i], preg[b2i + 1], preg[b2i + 4], preg[b2i + 5]);
    f16x8 af = __builtin_bit_cast(f16x8, pk);
    #pragma unroll
    for (int ct = 0; ct < 4; ++ct) {
      uint4 braw = *(const uint4*)&bbase[((ks * 8 + nh * 4 + ct) * 64 + l) * 8];
      f16x8 bfr = __builtin_bit_cast(f16x8, braw);
      acc[ct] = __builtin_amdgcn_mfma_f32_32x32x16_f16(af, bfr, acc[ct], 0, 0, 0);
    }
  }

  ushort* dst = all_rel_h + (size_t)(b * 128) * 1024;
  int ebase = r * 256 + nh * 128 + (l & 31);
  int half4 = (l >> 5) << 2;
  #pragma unroll
  for (int ct = 0; ct < 4; ++ct)
    #pragma unroll
    for (int g = 0; g < 16; ++g) {
      int i = rowq * 32 + (g & 3) + 8 * (g >> 2) + half4;
      dst[(size_t)i * 1024 + ebase + ct * 32] = to_h(acc[ct][g]);
    }
}

// ---------------- mlp1: hidden = relu(all_rel@Wa1+ba1), fp16 out ----------------
// grid (cq4, rt16) = 64 blocks; wave w -> ct = cq*4+w (32 cols); K=1024.
__global__ __launch_bounds__(256) void k_mlp1(
    const ushort* __restrict__ all_rel_h, const ushort* __restrict__ Wa1swz,
    const float* __restrict__ ba1, ushort* __restrict__ hiddenh)
{
  int cq = blockIdx.x, rt = blockIdx.y;
  int t = threadIdx.x, w = t >> 6, l = t & 63;
  __shared__ uint Ah[32][514];
  const uint* Ag = (const uint*)all_rel_h + (size_t)rt * 32 * 512;
  #pragma unroll
  for (int q = 0; q < 16; ++q) {
    int lin = q * 256 + t;
    int row = lin >> 7, c4 = (lin & 127) * 4;
    *(uint4*)&Ah[row][c4] = *(const uint4*)&Ag[row * 512 + c4];
  }
  __syncthreads();

  int m31 = l & 31, hi = l >> 5, hi2 = hi * 2;
  int ct = cq * 4 + w;
  f32x16 acc;
  #pragma unroll
  for (int e = 0; e < 16; ++e) acc[e] = 0.f;
  for (int ks = 0; ks < 64; ++ks) {
    int u0 = ks * 8 + hi2;
    uint2 xa = *(const uint2*)&Ah[m31][u0];
    uint2 xb = *(const uint2*)&Ah[m31][u0 + 4];
    uint4 a4 = make_uint4(xa.x, xa.y, xb.x, xb.y);
    f16x8 af = __builtin_bit_cast(f16x8, a4);
    uint4 braw = *(const uint4*)&Wa1swz[(size_t)((ks * 16 + ct) * 64 + l) * 8];
    f16x8 bfr = __builtin_bit_cast(f16x8, braw);
    acc = __builtin_amdgcn_mfma_f32_32x32x16_f16(af, bfr, acc, 0, 0, 0);
  }
  int e = ct * 32 + m31;
  float bv = ba1[e];
  #pragma unroll
  for (int g = 0; g < 16; ++g) {
    int row = (g & 3) + 8 * (g >> 2) + 4 * hi;
    hiddenh[(size_t)(rt * 32 + row) * 512 + e] = to_h(fmaxf(acc[g] + bv, 0.f));
  }
}

// ---------------- mlp2: out = hidden@Wa2+ba2, fp32 out ----------------
// grid (cq2, rt16) = 32 blocks; wave w -> ct = cq*4+w; K=512.
__global__ __launch_bounds__(256) void k_mlp2(
    const ushort* __restrict__ hiddenh, const ushort* __restrict__ Wa2swz,
    const float* __restrict__ ba2, float* __restrict__ out)
{
  int cq = blockIdx.x, rt = blockIdx.y;
  int t = threadIdx.x, w = t >> 6, l = t & 63;
  __shared__ uint Ah[32][258];
  const uint* Ag = (const uint*)hiddenh + (size_t)rt * 32 * 256;
  #pragma unroll
  for (int q = 0; q < 8; ++q) {
    int lin = q * 256 + t;
    int row = lin >> 6, c4 = (lin & 63) * 4;
    *(uint4*)&Ah[row][c4] = *(const uint4*)&Ag[row * 256 + c4];
  }
  __syncthreads();

  int m31 = l & 31, hi = l >> 5, hi2 = hi * 2;
  int ct = cq * 4 + w;
  f32x16 acc;
  #pragma unroll
  for (int e = 0; e < 16; ++e) acc[e] = 0.f;
  for (int ks = 0; ks < 32; ++ks) {
    int u0 = ks * 8 + hi2;
    uint2 xa = *(const uint2*)&Ah[m31][u0];
    uint2 xb = *(const uint2*)&Ah[m31][u0 + 4];
    uint4 a4 = make_uint4(xa.x, xa.y, xb.x, xb.y);
    f16x8 af = __builtin_bit_cast(f16x8, a4);
    uint4 braw = *(const uint4*)&Wa2swz[(size_t)((ks * 8 + ct) * 64 + l) * 8];
    f16x8 bfr = __builtin_bit_cast(f16x8, braw);
    acc = __builtin_amdgcn_mfma_f32_32x32x16_f16(af, bfr, acc, 0, 0, 0);
  }
  int e = ct * 32 + m31;
  float bv = ba2[e];
  #pragma unroll
  for (int g = 0; g < 16; ++g) {
    int row = (g & 3) + 8 * (g >> 2) + 4 * hi;
    out[(size_t)(rt * 32 + row) * 256 + e] = acc[g] + bv;
  }
}

extern "C" void kernel_launch(void* const* d_in, const int* in_sizes, int n_in,
                              void* d_out, int out_size, void* d_ws, size_t ws_size,
                              hipStream_t stream) {
  const float* f1  = (const float*)d_in[0];
  const float* f2  = (const float*)d_in[1];
  const float* W1  = (const float*)d_in[2];
  const float* b1  = (const float*)d_in[3];
  const float* W2  = (const float*)d_in[4];
  const float* b2  = (const float*)d_in[5];
  const float* w3  = (const float*)d_in[6];
  const float* b3  = (const float*)d_in[7];
  const float* Wa1 = (const float*)d_in[8];
  const float* ba1 = (const float*)d_in[9];
  const float* Wa2 = (const float*)d_in[10];
  const float* ba2 = (const float*)d_in[11];
  float* out = (float*)d_out;
  float* ws = (float*)d_ws;

  // Workspace (float offsets):
  uint*   f1hp     = (uint*)ws;                   // @0,     256KB
  uint*   f2hp     = (uint*)(ws + 65536);         // @256KB, 256KB
  ushort* h1p      = (ushort*)(ws + 131072);      // @512KB, 1MB
  ushort* h2       = (ushort*)(ws + 393216);      // @1.5MB, 1MB
  float*  scores   = ws + 655360;                 // @2.5MB, 1MB
  ushort* all_relh = (ushort*)(ws + 917504);      // @3.5MB, 1MB
  ushort* W1swz    = (ushort*)(ws + 1179648);     // @4.5MB, 1MB
  ushort* W2swz    = (ushort*)(ws + 1441792);     // @5.5MB, 256KB
  ushort* f2swz    = (ushort*)(ws + 1507328);     // @5.75MB,256KB
  ushort* Wa1swz   = (ushort*)(ws + 1572864);     // @6MB,   1MB
  ushort* Wa2swz   = (ushort*)(ws + 1835008);     // @7MB,   256KB
  ushort* hiddenh  = (ushort*)(ws + 1900544);     // @7.25MB,512KB

  hipLaunchKernelGGL(k_prep, dim3(320), dim3(256), 0, stream,
                     f1, f2, W1, W2, Wa1, Wa2,
                     f1hp, f2hp, W1swz, W2swz, f2swz, Wa1swz, Wa2swz);
  hipLaunchKernelGGL(k_proj_mfma, dim3(128), dim3(256), 0, stream,
                     f1hp, f2hp, W1swz, b1, h1p, h2);
  hipLaunchKernelGGL(k_scores_mfma, dim3(2048), dim3(256), 0, stream,
                     h1p, h2, W2swz, b2, w3, b3, scores);
  hipLaunchKernelGGL(k_softrel_mfma, dim3(128), dim3(64), 0, stream,
                     scores, f2swz, all_relh);
  hipLaunchKernelGGL(k_mlp1, dim3(4, 16), dim3(256), 0, stream,
                     all_relh, Wa1swz, ba1, hiddenh);
  hipLaunchKernelGGL(k_mlp2, dim3(2, 16), dim3(256), 0, stream,
                     hiddenh, Wa2swz, ba2, out);
}

// Round 12
// 62.348 us; speedup vs baseline: 1.2741x; 1.0358x over previous
//
#include <hip/hip_runtime.h>

// Shapes: B=4, N1=N2=128, D=256, R=4, E=D/2=128
// Pipeline (6 dispatches, everything matmul-shaped on fp16 MFMA):
//   1 k_prep      : cast f1/f2 -> fp16; swizzle W1/W2/f2/Wa1/Wa2 into B-fragment order
//   2 k_proj_mfma : h1p/h2 = f@W1(+b1), fp16 MFMA, packed fp16 out
//   3 k_scores    : scores via fp16 MFMA, 2x2 micro-tile per wave, B prefetch
//   4 k_softrel   : softmax + rel via fp16 MFMA, 256 x 1-wave blocks, tree reduce
//   5 k_mlp1      : hidden = relu(all_rel@Wa1+ba1), fp16 MFMA, fp16 out
//   6 k_mlp2      : out = hidden@Wa2+ba2, fp16 MFMA, fp32 out

typedef _Float16 f16x8 __attribute__((ext_vector_type(8)));
typedef float f32x16 __attribute__((ext_vector_type(16)));

static __device__ __forceinline__ ushort to_h(float f) {
  _Float16 h = (_Float16)f;
  return __builtin_bit_cast(ushort, h);
}
static __device__ __forceinline__ uint pack2(float a, float b) {
  return (uint)to_h(a) | ((uint)to_h(b) << 16);
}
static __device__ __forceinline__ uint pk_add(uint a, uint b) {
  uint r;
  asm("v_pk_add_f16 %0, %1, %2" : "=v"(r) : "v"(a), "v"(b));
  return r;
}
static __device__ __forceinline__ uint pk_relu(uint a) {
  uint r;
  asm("v_pk_max_f16 %0, %1, %2" : "=v"(r) : "v"(a), "v"(0u));
  return r;
}

// ---------------- prep: casts + all fragment swizzles (flat grid of 320) ----------------
__global__ __launch_bounds__(256) void k_prep(
    const float* __restrict__ f1, const float* __restrict__ f2,
    const float* __restrict__ W1, const float* __restrict__ W2,
    const float* __restrict__ Wa1, const float* __restrict__ Wa2,
    uint* __restrict__ f1hp, uint* __restrict__ f2hp,
    ushort* __restrict__ W1swz, ushort* __restrict__ W2swz,
    ushort* __restrict__ f2swz, ushort* __restrict__ Wa1swz,
    ushort* __restrict__ Wa2swz)
{
  int blk = blockIdx.x, t = threadIdx.x;
  if (blk < 128) {
    int u = blk * 256 + t;
    float4 a = *(const float4*)&f1[u * 4];
    float4 b = *(const float4*)&f2[u * 4];
    *(uint2*)&f1hp[u * 2] = make_uint2(pack2(a.x, a.y), pack2(a.z, a.w));
    *(uint2*)&f2hp[u * 2] = make_uint2(pack2(b.x, b.y), pack2(b.z, b.w));
    return;
  }
  if (blk < 256) {
    // W1 -> B-frag order [r][half][ks16][ct8][l64][j8]
    int unit = blk - 128;
    int r = unit >> 5, half = (unit >> 4) & 1, ks = unit & 15;
    int l = t & 63, ctq = t >> 6;
    #pragma unroll
    for (int ci = 0; ci < 2; ++ci) {
      int ct = ctq + ci * 4;
      int e = ct * 32 + (l & 31);
      ushort us[8];
      #pragma unroll
      for (int j = 0; j < 8; ++j) {
        int d = ks * 16 + ((l >> 5) * 4) + (j & 3) + ((j >> 2) * 8);
        us[j] = to_h(W1[(size_t)(r * 512 + half * 256 + d) * 256 + e]);
      }
      uint4 pk;
      pk.x = (uint)us[0] | ((uint)us[1] << 16);
      pk.y = (uint)us[2] | ((uint)us[3] << 16);
      pk.z = (uint)us[4] | ((uint)us[5] << 16);
      pk.w = (uint)us[6] | ((uint)us[7] << 16);
      *(uint4*)&W1swz[(size_t)((((r * 2 + half) * 16 + ks) * 8 + ct) * 64 + l) * 8] = pk;
    }
    return;
  }
  if (blk < 272) {
    // W2 -> [r][ks16][ct4][l64][j8]
    int sub = blk - 256;
    int r = sub >> 2, ks0 = (sub & 3) * 4;
    int ct = t >> 6, l = t & 63;
    #pragma unroll
    for (int ko = 0; ko < 4; ++ko) {
      int ks = ks0 + ko;
      ushort us[8];
      #pragma unroll
      for (int j = 0; j < 8; ++j) {
        int d = ks * 16 + ((j >> 2) * 8) + ((l >> 5) * 4) + (j & 3);
        int e = ct * 32 + (l & 31);
        us[j] = to_h(W2[(r * 256 + d) * 128 + e]);
      }
      uint4 pk;
      pk.x = (uint)us[0] | ((uint)us[1] << 16);
      pk.y = (uint)us[2] | ((uint)us[3] << 16);
      pk.z = (uint)us[4] | ((uint)us[5] << 16);
      pk.w = (uint)us[6] | ((uint)us[7] << 16);
      *(uint4*)&W2swz[(((r * 16 + ks) * 4 + ct) * 64 + l) * 8] = pk;
    }
    return;
  }
  if (blk < 288) {
    // f2 -> [b][ks8][ctg8][l64][j8]
    int sub = blk - 272;
    int w = t >> 6, l = t & 63;
    #pragma unroll
    for (int ko = 0; ko < 4; ++ko) {
      int u = sub * 16 + w * 4 + ko;
      int b = u >> 6, ks = (u >> 3) & 7, ctg = u & 7;
      ushort us[8];
      #pragma unroll
      for (int j = 0; j < 8; ++j) {
        int k = ks * 16 + ((l >> 5) * 4) + (j & 3) + ((j >> 2) * 8);
        int n = ctg * 32 + (l & 31);
        us[j] = to_h(f2[((size_t)b * 128 + k) * 256 + n]);
      }
      uint4 pk;
      pk.x = (uint)us[0] | ((uint)us[1] << 16);
      pk.y = (uint)us[2] | ((uint)us[3] << 16);
      pk.z = (uint)us[4] | ((uint)us[5] << 16);
      pk.w = (uint)us[6] | ((uint)us[7] << 16);
      *(uint4*)&f2swz[(((b * 8 + ks) * 8 + ctg) * 64 + l) * 8] = pk;
    }
    return;
  }
  if (blk < 304) {
    // Wa1[1024,512] -> [ks64][ct16][l64][j8]
    int sub = blk - 288;
    #pragma unroll
    for (int ko = 0; ko < 16; ++ko) {
      int id = sub * 4096 + ko * 256 + t;
      int ks = id >> 10, ct = (id >> 6) & 15, l = id & 63;
      ushort us[8];
      #pragma unroll
      for (int j = 0; j < 8; ++j) {
        int d = ks * 16 + ((l >> 5) * 4) + (j & 3) + ((j >> 2) * 8);
        int e = ct * 32 + (l & 31);
        us[j] = to_h(Wa1[(size_t)d * 512 + e]);
      }
      uint4 pk;
      pk.x = (uint)us[0] | ((uint)us[1] << 16);
      pk.y = (uint)us[2] | ((uint)us[3] << 16);
      pk.z = (uint)us[4] | ((uint)us[5] << 16);
      pk.w = (uint)us[6] | ((uint)us[7] << 16);
      *(uint4*)&Wa1swz[(size_t)id * 8] = pk;
    }
    return;
  }
  {
    // Wa2[512,256] -> [ks32][ct8][l64][j8]
    int sub = blk - 304;
    #pragma unroll
    for (int ko = 0; ko < 4; ++ko) {
      int id = sub * 1024 + ko * 256 + t;
      int ks = id >> 9, ct = (id >> 6) & 7, l = id & 63;
      ushort us[8];
      #pragma unroll
      for (int j = 0; j < 8; ++j) {
        int d = ks * 16 + ((l >> 5) * 4) + (j & 3) + ((j >> 2) * 8);
        int e = ct * 32 + (l & 31);
        us[j] = to_h(Wa2[(size_t)d * 256 + e]);
      }
      uint4 pk;
      pk.x = (uint)us[0] | ((uint)us[1] << 16);
      pk.y = (uint)us[2] | ((uint)us[3] << 16);
      pk.z = (uint)us[4] | ((uint)us[5] << 16);
      pk.w = (uint)us[6] | ((uint)us[7] << 16);
      *(uint4*)&Wa2swz[(size_t)id * 8] = pk;
    }
    return;
  }
}

// ---------------- projection via fp16 MFMA ----------------
__global__ __launch_bounds__(256) void k_proj_mfma(
    const uint* __restrict__ f1hp, const uint* __restrict__ f2hp,
    const ushort* __restrict__ W1swz, const float* __restrict__ b1,
    ushort* __restrict__ h1p, ushort* __restrict__ h2)
{
  int bid = blockIdx.x;
  int it = bid & 3;
  int half = (bid >> 2) & 1;
  int r = (bid >> 3) & 3;
  int b = bid >> 5;
  int t = threadIdx.x, w = t >> 6, l = t & 63;
  __shared__ uint Au[32][132];

  const uint* src = (half ? f2hp : f1hp) + (size_t)b * 16384 + it * 32 * 128;
  #pragma unroll
  for (int q = 0; q < 4; ++q) {
    int lin = q * 256 + t;
    int row = lin >> 5, c4 = (lin & 31) * 4;
    *(uint4*)&Au[row][c4] = *(const uint4*)&src[row * 128 + c4];
  }
  __syncthreads();

  int m31 = l & 31, hi = l >> 5, hi2 = hi * 2;
  f32x16 acc0, acc1;
  #pragma unroll
  for (int e = 0; e < 16; ++e) { acc0[e] = 0.f; acc1[e] = 0.f; }

  const ushort* bb = W1swz + (size_t)(r * 2 + half) * 65536;
  for (int ks = 0; ks < 16; ++ks) {
    int u0 = ks * 8 + hi2;
    uint2 xa = *(const uint2*)&Au[m31][u0];
    uint2 xb = *(const uint2*)&Au[m31][u0 + 4];
    uint4 a4 = make_uint4(xa.x, xa.y, xb.x, xb.y);
    f16x8 af = __builtin_bit_cast(f16x8, a4);
    uint4 br0 = *(const uint4*)&bb[((ks * 8 + w * 2 + 0) * 64 + l) * 8];
    uint4 br1 = *(const uint4*)&bb[((ks * 8 + w * 2 + 1) * 64 + l) * 8];
    f16x8 bf0 = __builtin_bit_cast(f16x8, br0);
    f16x8 bf1 = __builtin_bit_cast(f16x8, br1);
    acc0 = __builtin_amdgcn_mfma_f32_32x32x16_f16(af, bf0, acc0, 0, 0, 0);
    acc1 = __builtin_amdgcn_mfma_f32_32x32x16_f16(af, bf1, acc1, 0, 0, 0);
  }

  ushort* ho = (half ? h2 : h1p) + ((size_t)((b * 4 + r) * 128 + it * 32)) * 256;
  #pragma unroll
  for (int ctl = 0; ctl < 2; ++ctl) {
    int e = (w * 2 + ctl) * 32 + m31;
    float bv = half ? 0.f : b1[r * 256 + e];
    #pragma unroll
    for (int g = 0; g < 16; ++g) {
      int row = (g & 3) + 8 * (g >> 2) + 4 * hi;
      ho[row * 256 + e] = to_h((ctl ? acc1[g] : acc0[g]) + bv);
    }
  }
}

// ---------------- fp16 MFMA scores: 2x2 micro-tile per wave, B prefetch ----------------
__global__ __launch_bounds__(256, 4) void k_scores_mfma(
    const ushort* __restrict__ h1p, const ushort* __restrict__ h2,
    const ushort* __restrict__ W2swz, const float* __restrict__ b2,
    const float* __restrict__ w3, const float* __restrict__ b3,
    float* __restrict__ scores)
{
  int bid = blockIdx.x;        // 2048: b(4) x r(4) x it(16) x jt(8)
  int jt = bid & 7;
  int it = (bid >> 3) & 15;
  int r  = (bid >> 7) & 3;
  int b  = bid >> 9;
  int t = threadIdx.x, w = t >> 6, l = t & 63;
  __shared__ uint h1u[8][132];
  __shared__ uint h2u[16][132];
  __shared__ float xch[4][2][2][16];

  const uint* h1g = (const uint*)h1p + ((size_t)((b * 4 + r) * 128 + it * 8)) * 128;
  const uint* h2g = (const uint*)h2  + ((size_t)((b * 4 + r) * 128 + jt * 16)) * 128;
  {
    int row = t >> 5, c4 = (t & 31) * 4;
    *(uint4*)&h1u[row][c4] = *(const uint4*)&h1g[row * 128 + c4];
    *(uint4*)&h2u[row][c4] = *(const uint4*)&h2g[row * 128 + c4];
    *(uint4*)&h2u[row + 8][c4] = *(const uint4*)&h2g[(row + 8) * 128 + c4];
  }

  f32x16 acc[2][2];
  #pragma unroll
  for (int i = 0; i < 2; ++i)
    #pragma unroll
    for (int c = 0; c < 2; ++c)
      #pragma unroll
      for (int e = 0; e < 16; ++e) acc[i][c][e] = 0.f;

  int rtp = w & 1, ctp = w >> 1;
  int hi2 = (l >> 5) * 2;
  int m31 = l & 31;
  int jrow = m31 & 15;
  int irow0 = (rtp * 2 + 0) * 2 + (m31 >> 4);
  int irow1 = (rtp * 2 + 1) * 2 + (m31 >> 4);
  const ushort* bptr = W2swz + r * (16 * 4 * 64 * 8) + (((ctp * 2) * 64 + l) * 8);

  __syncthreads();

  const uint* h1r0 = &h1u[irow0][0];
  const uint* h1r1 = &h1u[irow1][0];
  const uint* h2r  = &h2u[jrow][0];
  // B prefetch pipeline: nb{0,1} hold fragments for iteration ks.
  uint4 nb0 = *(const uint4*)&bptr[0];
  uint4 nb1 = *(const uint4*)&bptr[512];
  #pragma unroll 2
  for (int ks = 0; ks < 16; ++ks) {
    uint4 b0 = nb0, b1 = nb1;
    if (ks < 15) {
      nb0 = *(const uint4*)&bptr[(ks + 1) * 2048];
      nb1 = *(const uint4*)&bptr[(ks + 1) * 2048 + 512];
    }
    int u0 = ks * 8 + hi2;
    uint2 ya  = *(const uint2*)&h2r[u0];
    uint2 yb  = *(const uint2*)&h2r[u0 + 4];
    uint2 xa0 = *(const uint2*)&h1r0[u0];
    uint2 xb0 = *(const uint2*)&h1r0[u0 + 4];
    uint2 xa1 = *(const uint2*)&h1r1[u0];
    uint2 xb1 = *(const uint2*)&h1r1[u0 + 4];
    uint4 pk0, pk1;
    pk0.x = pk_relu(pk_add(xa0.x, ya.x));
    pk0.y = pk_relu(pk_add(xa0.y, ya.y));
    pk0.z = pk_relu(pk_add(xb0.x, yb.x));
    pk0.w = pk_relu(pk_add(xb0.y, yb.y));
    pk1.x = pk_relu(pk_add(xa1.x, ya.x));
    pk1.y = pk_relu(pk_add(xa1.y, ya.y));
    pk1.z = pk_relu(pk_add(xb1.x, yb.x));
    pk1.w = pk_relu(pk_add(xb1.y, yb.y));
    f16x8 af0 = __builtin_bit_cast(f16x8, pk0);
    f16x8 af1 = __builtin_bit_cast(f16x8, pk1);
    f16x8 bf0 = __builtin_bit_cast(f16x8, b0);
    f16x8 bf1 = __builtin_bit_cast(f16x8, b1);
    acc[0][0] = __builtin_amdgcn_mfma_f32_32x32x16_f16(af0, bf0, acc[0][0], 0, 0, 0);
    acc[0][1] = __builtin_amdgcn_mfma_f32_32x32x16_f16(af0, bf1, acc[0][1], 0, 0, 0);
    acc[1][0] = __builtin_amdgcn_mfma_f32_32x32x16_f16(af1, bf0, acc[1][0], 0, 0, 0);
    acc[1][1] = __builtin_amdgcn_mfma_f32_32x32x16_f16(af1, bf1, acc[1][1], 0, 0, 0);
  }

  float sp[2][16];
  #pragma unroll
  for (int i = 0; i < 2; ++i)
    #pragma unroll
    for (int g = 0; g < 16; ++g) sp[i][g] = 0.f;
  #pragma unroll
  for (int ctl = 0; ctl < 2; ++ctl) {
    int e = (ctp * 2 + ctl) * 32 + m31;
    float w3v = w3[r * 128 + e];
    float b2v = b2[r * 128 + e];
    #pragma unroll
    for (int i = 0; i < 2; ++i)
      #pragma unroll
      for (int g = 0; g < 16; ++g)
        sp[i][g] = fmaf(w3v, fmaxf(acc[i][ctl][g] + b2v, 0.f), sp[i][g]);
  }
  #pragma unroll
  for (int off = 16; off >= 1; off >>= 1)
    #pragma unroll
    for (int i = 0; i < 2; ++i)
      #pragma unroll
      for (int g = 0; g < 16; ++g)
        sp[i][g] += __shfl_xor(sp[i][g], off, 64);
  int hi = l >> 5;
  if (m31 == 0) {
    #pragma unroll
    for (int i = 0; i < 2; ++i)
      #pragma unroll
      for (int g = 0; g < 16; ++g)
        xch[w][i][hi][g] = sp[i][g];
  }
  __syncthreads();
  if (w < 2 && m31 == 0) {
    float b3v = b3[r];
    float* sc_base = scores + (((b * 4 + r) * 128 + it * 8) * 128) + jt * 16;
    #pragma unroll
    for (int i = 0; i < 2; ++i)
      #pragma unroll
      for (int g = 0; g < 16; ++g) {
        float s = xch[w][i][hi][g] + xch[w + 2][i][hi][g] + b3v;
        int p = (w * 2 + i) * 32 + (g & 3) + 8 * (g >> 2) + hi * 4;
        sc_base[(p >> 4) * 128 + (p & 15)] = s;
      }
  }
}

// ---------------- softmax + rel; 256 x 1-wave blocks, tree reductions ----------------
__global__ __launch_bounds__(64, 1) void k_softrel_mfma(
    const float* __restrict__ scores, const ushort* __restrict__ f2swz,
    ushort* __restrict__ all_rel_h)
{
  int bid = blockIdx.x;         // 256: b(4) x r(4) x nh(2) x rowq(4) x ctp(2)
  int ctp  = bid & 1;
  int rowq = (bid >> 1) & 3;
  int nh   = (bid >> 3) & 1;
  int r    = (bid >> 4) & 3;
  int b    = bid >> 6;
  int l = threadIdx.x;
  int row = rowq * 32 + (l & 31);
  const float* srow = scores + ((size_t)(b * 4 + r) * 128 + row) * 128;

  float p[128];
  #pragma unroll
  for (int q = 0; q < 32; ++q) {
    float4 v = *(const float4*)&srow[q * 4];
    p[q * 4 + 0] = v.x; p[q * 4 + 1] = v.y;
    p[q * 4 + 2] = v.z; p[q * 4 + 3] = v.w;
  }
  // tree max: 8 parallel chains of 16, then combine
  float mm[8];
  #pragma unroll
  for (int c = 0; c < 8; ++c) mm[c] = p[c * 16];
  #pragma unroll
  for (int k = 1; k < 16; ++k)
    #pragma unroll
    for (int c = 0; c < 8; ++c) mm[c] = fmaxf(mm[c], p[c * 16 + k]);
  float m = fmaxf(fmaxf(fmaxf(mm[0], mm[1]), fmaxf(mm[2], mm[3])),
                  fmaxf(fmaxf(mm[4], mm[5]), fmaxf(mm[6], mm[7])));
  // exp + tree sum
  float ss[8];
  #pragma unroll
  for (int c = 0; c < 8; ++c) ss[c] = 0.f;
  #pragma unroll
  for (int k = 0; k < 16; ++k)
    #pragma unroll
    for (int c = 0; c < 8; ++c) {
      p[c * 16 + k] = __expf(p[c * 16 + k] - m);
      ss[c] += p[c * 16 + k];
    }
  float sum = ((ss[0] + ss[1]) + (ss[2] + ss[3])) + ((ss[4] + ss[5]) + (ss[6] + ss[7]));
  float inv = 1.f / sum;
  uint preg[64];
  #pragma unroll
  for (int q = 0; q < 64; ++q)
    preg[q] = pack2(p[2 * q] * inv, p[2 * q + 1] * inv);

  f32x16 acc[2];
  #pragma unroll
  for (int c = 0; c < 2; ++c)
    #pragma unroll
    for (int e = 0; e < 16; ++e) acc[c][e] = 0.f;

  int hi2 = (l >> 5) * 2;
  const ushort* bbase = f2swz + (size_t)b * (8 * 8 * 64 * 8);
  #pragma unroll
  for (int ks = 0; ks < 8; ++ks) {
    int b2i = ks * 8 + hi2;
    uint4 pk = make_uint4(preg[b2i], preg[b2i + 1], preg[b2i + 4], preg[b2i + 5]);
    f16x8 af = __builtin_bit_cast(f16x8, pk);
    #pragma unroll
    for (int ctl = 0; ctl < 2; ++ctl) {
      int ct = nh * 4 + ctp * 2 + ctl;
      uint4 braw = *(const uint4*)&bbase[((ks * 8 + ct) * 64 + l) * 8];
      f16x8 bfr = __builtin_bit_cast(f16x8, braw);
      acc[ctl] = __builtin_amdgcn_mfma_f32_32x32x16_f16(af, bfr, acc[ctl], 0, 0, 0);
    }
  }

  ushort* dst = all_rel_h + (size_t)(b * 128) * 1024;
  int ebase = r * 256 + nh * 128 + ctp * 64 + (l & 31);
  int half4 = (l >> 5) << 2;
  #pragma unroll
  for (int ctl = 0; ctl < 2; ++ctl)
    #pragma unroll
    for (int g = 0; g < 16; ++g) {
      int i = rowq * 32 + (g & 3) + 8 * (g >> 2) + half4;
      dst[(size_t)i * 1024 + ebase + ctl * 32] = to_h(acc[ctl][g]);
    }
}

// ---------------- mlp1: hidden = relu(all_rel@Wa1+ba1), fp16 out ----------------
__global__ __launch_bounds__(256) void k_mlp1(
    const ushort* __restrict__ all_rel_h, const ushort* __restrict__ Wa1swz,
    const float* __restrict__ ba1, ushort* __restrict__ hiddenh)
{
  int cq = blockIdx.x, rt = blockIdx.y;
  int t = threadIdx.x, w = t >> 6, l = t & 63;
  __shared__ uint Ah[32][514];
  const uint* Ag = (const uint*)all_rel_h + (size_t)rt * 32 * 512;
  #pragma unroll
  for (int q = 0; q < 16; ++q) {
    int lin = q * 256 + t;
    int row = lin >> 7, c4 = (lin & 127) * 4;
    *(uint4*)&Ah[row][c4] = *(const uint4*)&Ag[row * 512 + c4];
  }
  __syncthreads();

  int m31 = l & 31, hi = l >> 5, hi2 = hi * 2;
  int ct = cq * 4 + w;
  f32x16 acc;
  #pragma unroll
  for (int e = 0; e < 16; ++e) acc[e] = 0.f;
  for (int ks = 0; ks < 64; ++ks) {
    int u0 = ks * 8 + hi2;
    uint2 xa = *(const uint2*)&Ah[m31][u0];
    uint2 xb = *(const uint2*)&Ah[m31][u0 + 4];
    uint4 a4 = make_uint4(xa.x, xa.y, xb.x, xb.y);
    f16x8 af = __builtin_bit_cast(f16x8, a4);
    uint4 braw = *(const uint4*)&Wa1swz[(size_t)((ks * 16 + ct) * 64 + l) * 8];
    f16x8 bfr = __builtin_bit_cast(f16x8, braw);
    acc = __builtin_amdgcn_mfma_f32_32x32x16_f16(af, bfr, acc, 0, 0, 0);
  }
  int e = ct * 32 + m31;
  float bv = ba1[e];
  #pragma unroll
  for (int g = 0; g < 16; ++g) {
    int row = (g & 3) + 8 * (g >> 2) + 4 * hi;
    hiddenh[(size_t)(rt * 32 + row) * 512 + e] = to_h(fmaxf(acc[g] + bv, 0.f));
  }
}

// ---------------- mlp2: out = hidden@Wa2+ba2, fp32 out ----------------
__global__ __launch_bounds__(256) void k_mlp2(
    const ushort* __restrict__ hiddenh, const ushort* __restrict__ Wa2swz,
    const float* __restrict__ ba2, float* __restrict__ out)
{
  int cq = blockIdx.x, rt = blockIdx.y;
  int t = threadIdx.x, w = t >> 6, l = t & 63;
  __shared__ uint Ah[32][258];
  const uint* Ag = (const uint*)hiddenh + (size_t)rt * 32 * 256;
  #pragma unroll
  for (int q = 0; q < 8; ++q) {
    int lin = q * 256 + t;
    int row = lin >> 6, c4 = (lin & 63) * 4;
    *(uint4*)&Ah[row][c4] = *(const uint4*)&Ag[row * 256 + c4];
  }
  __syncthreads();

  int m31 = l & 31, hi = l >> 5, hi2 = hi * 2;
  int ct = cq * 4 + w;
  f32x16 acc;
  #pragma unroll
  for (int e = 0; e < 16; ++e) acc[e] = 0.f;
  for (int ks = 0; ks < 32; ++ks) {
    int u0 = ks * 8 + hi2;
    uint2 xa = *(const uint2*)&Ah[m31][u0];
    uint2 xb = *(const uint2*)&Ah[m31][u0 + 4];
    uint4 a4 = make_uint4(xa.x, xa.y, xb.x, xb.y);
    f16x8 af = __builtin_bit_cast(f16x8, a4);
    uint4 braw = *(const uint4*)&Wa2swz[(size_t)((ks * 8 + ct) * 64 + l) * 8];
    f16x8 bfr = __builtin_bit_cast(f16x8, braw);
    acc = __builtin_amdgcn_mfma_f32_32x32x16_f16(af, bfr, acc, 0, 0, 0);
  }
  int e = ct * 32 + m31;
  float bv = ba2[e];
  #pragma unroll
  for (int g = 0; g < 16; ++g) {
    int row = (g & 3) + 8 * (g >> 2) + 4 * hi;
    out[(size_t)(rt * 32 + row) * 256 + e] = acc[g] + bv;
  }
}

extern "C" void kernel_launch(void* const* d_in, const int* in_sizes, int n_in,
                              void* d_out, int out_size, void* d_ws, size_t ws_size,
                              hipStream_t stream) {
  const float* f1  = (const float*)d_in[0];
  const float* f2  = (const float*)d_in[1];
  const float* W1  = (const float*)d_in[2];
  const float* b1  = (const float*)d_in[3];
  const float* W2  = (const float*)d_in[4];
  const float* b2  = (const float*)d_in[5];
  const float* w3  = (const float*)d_in[6];
  const float* b3  = (const float*)d_in[7];
  const float* Wa1 = (const float*)d_in[8];
  const float* ba1 = (const float*)d_in[9];
  const float* Wa2 = (const float*)d_in[10];
  const float* ba2 = (const float*)d_in[11];
  float* out = (float*)d_out;
  float* ws = (float*)d_ws;

  uint*   f1hp     = (uint*)ws;                   // @0,     256KB
  uint*   f2hp     = (uint*)(ws + 65536);         // @256KB, 256KB
  ushort* h1p      = (ushort*)(ws + 131072);      // @512KB, 1MB
  ushort* h2       = (ushort*)(ws + 393216);      // @1.5MB, 1MB
  float*  scores   = ws + 655360;                 // @2.5MB, 1MB
  ushort* all_relh = (ushort*)(ws + 917504);      // @3.5MB, 1MB
  ushort* W1swz    = (ushort*)(ws + 1179648);     // @4.5MB, 1MB
  ushort* W2swz    = (ushort*)(ws + 1441792);     // @5.5MB, 256KB
  ushort* f2swz    = (ushort*)(ws + 1507328);     // @5.75MB,256KB
  ushort* Wa1swz   = (ushort*)(ws + 1572864);     // @6MB,   1MB
  ushort* Wa2swz   = (ushort*)(ws + 1835008);     // @7MB,   256KB
  ushort* hiddenh  = (ushort*)(ws + 1900544);     // @7.25MB,512KB

  hipLaunchKernelGGL(k_prep, dim3(320), dim3(256), 0, stream,
                     f1, f2, W1, W2, Wa1, Wa2,
                     f1hp, f2hp, W1swz, W2swz, f2swz, Wa1swz, Wa2swz);
  hipLaunchKernelGGL(k_proj_mfma, dim3(128), dim3(256), 0, stream,
                     f1hp, f2hp, W1swz, b1, h1p, h2);
  hipLaunchKernelGGL(k_scores_mfma, dim3(2048), dim3(256), 0, stream,
                     h1p, h2, W2swz, b2, w3, b3, scores);
  hipLaunchKernelGGL(k_softrel_mfma, dim3(256), dim3(64), 0, stream,
                     scores, f2swz, all_relh);
  hipLaunchKernelGGL(k_mlp1, dim3(4, 16), dim3(256), 0, stream,
                     all_relh, Wa1swz, ba1, hiddenh);
  hipLaunchKernelGGL(k_mlp2, dim3(2, 16), dim3(256), 0, stream,
                     hiddenh, Wa2swz, ba2, out);
}

// Round 13
// 61.503 us; speedup vs baseline: 1.2916x; 1.0137x over previous
//
#include <hip/hip_runtime.h>

// Shapes: B=4, N1=N2=128, D=256, R=4, E=D/2=128
// Pipeline (5 dispatches, everything matmul-shaped on fp16 MFMA):
//   1 k_prepproj : [blk<128] proj h1p/h2 = f@W1(+b1) — self-cast f, raw-fp32 W1 frags
//                  [blk>=128] W2/f2/Wa1/Wa2 fragment swizzles
//   2 k_scores   : scores via fp16 MFMA, 2x2 micro-tile per wave, B prefetch
//   3 k_softrel  : softmax + rel via fp16 MFMA, 256 x 1-wave blocks, tree reduce
//   4 k_mlp1     : hidden = relu(all_rel@Wa1+ba1), fp16 MFMA, fp16 out
//   5 k_mlp2     : out = hidden@Wa2+ba2, fp16 MFMA, fp32 out

typedef _Float16 f16x8 __attribute__((ext_vector_type(8)));
typedef float f32x16 __attribute__((ext_vector_type(16)));

static __device__ __forceinline__ ushort to_h(float f) {
  _Float16 h = (_Float16)f;
  return __builtin_bit_cast(ushort, h);
}
static __device__ __forceinline__ uint pack2(float a, float b) {
  return (uint)to_h(a) | ((uint)to_h(b) << 16);
}
static __device__ __forceinline__ uint pk_add(uint a, uint b) {
  uint r;
  asm("v_pk_add_f16 %0, %1, %2" : "=v"(r) : "v"(a), "v"(b));
  return r;
}
static __device__ __forceinline__ uint pk_relu(uint a) {
  uint r;
  asm("v_pk_max_f16 %0, %1, %2" : "=v"(r) : "v"(a), "v"(0u));
  return r;
}

// ---------------- prep+proj: one kernel, flat grid of 192 ----------------
__global__ __launch_bounds__(256) void k_prepproj(
    const float* __restrict__ f1, const float* __restrict__ f2,
    const float* __restrict__ W1, const float* __restrict__ b1,
    const float* __restrict__ W2, const float* __restrict__ Wa1,
    const float* __restrict__ Wa2,
    ushort* __restrict__ W2swz, ushort* __restrict__ f2swz,
    ushort* __restrict__ Wa1swz, ushort* __restrict__ Wa2swz,
    ushort* __restrict__ h1p, ushort* __restrict__ h2)
{
  int blk = blockIdx.x, t = threadIdx.x;
  __shared__ uint Au[32][132];

  if (blk < 128) {
    // ---- projection: unit (b,r,half,it); self-cast f tile, raw W1 fragments ----
    int it = blk & 3;
    int half = (blk >> 2) & 1;
    int r = (blk >> 3) & 3;
    int b = blk >> 5;
    int w = t >> 6, l = t & 63;

    const float* src = (half ? f2 : f1) + (size_t)b * 32768 + it * 32 * 256;
    #pragma unroll
    for (int q = 0; q < 4; ++q) {
      int lin = q * 256 + t;          // [0,1024) uint4 units
      int row = lin >> 5;             // 32 uint4 per row
      int fo = (lin & 31) * 8;        // float offset in row
      float4 fa = *(const float4*)&src[row * 256 + fo];
      float4 fb = *(const float4*)&src[row * 256 + fo + 4];
      uint4 pk;
      pk.x = pack2(fa.x, fa.y); pk.y = pack2(fa.z, fa.w);
      pk.z = pack2(fb.x, fb.y); pk.w = pack2(fb.z, fb.w);
      *(uint4*)&Au[row][(lin & 31) * 4] = pk;
    }
    __syncthreads();

    int m31 = l & 31, hi = l >> 5, hi2 = hi * 2;
    f32x16 acc0, acc1;
    #pragma unroll
    for (int e = 0; e < 16; ++e) { acc0[e] = 0.f; acc1[e] = 0.f; }

    const float* W1b = W1 + (size_t)(r * 512 + half * 256) * 256;
    int e0 = (w * 2 + 0) * 32 + m31;
    int e1 = (w * 2 + 1) * 32 + m31;
    for (int ks = 0; ks < 16; ++ks) {
      int u0 = ks * 8 + hi2;
      uint2 xa = *(const uint2*)&Au[m31][u0];
      uint2 xb = *(const uint2*)&Au[m31][u0 + 4];
      uint4 a4 = make_uint4(xa.x, xa.y, xb.x, xb.y);
      f16x8 af = __builtin_bit_cast(f16x8, a4);
      int d00 = ks * 16 + hi * 4;
      const float* wr = W1b + (size_t)d00 * 256;
      // fragment j: d = d00 + (j&3) + (j>>2)*8
      uint4 b0, b1;
      b0.x = pack2(wr[0 * 256 + e0], wr[1 * 256 + e0]);
      b0.y = pack2(wr[2 * 256 + e0], wr[3 * 256 + e0]);
      b0.z = pack2(wr[8 * 256 + e0], wr[9 * 256 + e0]);
      b0.w = pack2(wr[10 * 256 + e0], wr[11 * 256 + e0]);
      b1.x = pack2(wr[0 * 256 + e1], wr[1 * 256 + e1]);
      b1.y = pack2(wr[2 * 256 + e1], wr[3 * 256 + e1]);
      b1.z = pack2(wr[8 * 256 + e1], wr[9 * 256 + e1]);
      b1.w = pack2(wr[10 * 256 + e1], wr[11 * 256 + e1]);
      f16x8 bf0 = __builtin_bit_cast(f16x8, b0);
      f16x8 bf1 = __builtin_bit_cast(f16x8, b1);
      acc0 = __builtin_amdgcn_mfma_f32_32x32x16_f16(af, bf0, acc0, 0, 0, 0);
      acc1 = __builtin_amdgcn_mfma_f32_32x32x16_f16(af, bf1, acc1, 0, 0, 0);
    }

    ushort* ho = (half ? h2 : h1p) + ((size_t)((b * 4 + r) * 128 + it * 32)) * 256;
    #pragma unroll
    for (int ctl = 0; ctl < 2; ++ctl) {
      int e = (w * 2 + ctl) * 32 + m31;
      float bv = half ? 0.f : b1[r * 256 + e];
      #pragma unroll
      for (int g = 0; g < 16; ++g) {
        int row = (g & 3) + 8 * (g >> 2) + 4 * hi;
        ho[row * 256 + e] = to_h((ctl ? acc1[g] : acc0[g]) + bv);
      }
    }
    return;
  }

  if (blk < 144) {
    // W2 -> [r][ks16][ct4][l64][j8]
    int sub = blk - 128;
    int r = sub >> 2, ks0 = (sub & 3) * 4;
    int ct = t >> 6, l = t & 63;
    #pragma unroll
    for (int ko = 0; ko < 4; ++ko) {
      int ks = ks0 + ko;
      ushort us[8];
      #pragma unroll
      for (int j = 0; j < 8; ++j) {
        int d = ks * 16 + ((j >> 2) * 8) + ((l >> 5) * 4) + (j & 3);
        int e = ct * 32 + (l & 31);
        us[j] = to_h(W2[(r * 256 + d) * 128 + e]);
      }
      uint4 pk;
      pk.x = (uint)us[0] | ((uint)us[1] << 16);
      pk.y = (uint)us[2] | ((uint)us[3] << 16);
      pk.z = (uint)us[4] | ((uint)us[5] << 16);
      pk.w = (uint)us[6] | ((uint)us[7] << 16);
      *(uint4*)&W2swz[(((r * 16 + ks) * 4 + ct) * 64 + l) * 8] = pk;
    }
    return;
  }
  if (blk < 160) {
    // f2 -> [b][ks8][ctg8][l64][j8]
    int sub = blk - 144;
    int w = t >> 6, l = t & 63;
    #pragma unroll
    for (int ko = 0; ko < 4; ++ko) {
      int u = sub * 16 + w * 4 + ko;
      int b = u >> 6, ks = (u >> 3) & 7, ctg = u & 7;
      ushort us[8];
      #pragma unroll
      for (int j = 0; j < 8; ++j) {
        int k = ks * 16 + ((l >> 5) * 4) + (j & 3) + ((j >> 2) * 8);
        int n = ctg * 32 + (l & 31);
        us[j] = to_h(f2[((size_t)b * 128 + k) * 256 + n]);
      }
      uint4 pk;
      pk.x = (uint)us[0] | ((uint)us[1] << 16);
      pk.y = (uint)us[2] | ((uint)us[3] << 16);
      pk.z = (uint)us[4] | ((uint)us[5] << 16);
      pk.w = (uint)us[6] | ((uint)us[7] << 16);
      *(uint4*)&f2swz[(((b * 8 + ks) * 8 + ctg) * 64 + l) * 8] = pk;
    }
    return;
  }
  if (blk < 176) {
    // Wa1[1024,512] -> [ks64][ct16][l64][j8]
    int sub = blk - 160;
    #pragma unroll
    for (int ko = 0; ko < 16; ++ko) {
      int id = sub * 4096 + ko * 256 + t;
      int ks = id >> 10, ct = (id >> 6) & 15, l = id & 63;
      ushort us[8];
      #pragma unroll
      for (int j = 0; j < 8; ++j) {
        int d = ks * 16 + ((l >> 5) * 4) + (j & 3) + ((j >> 2) * 8);
        int e = ct * 32 + (l & 31);
        us[j] = to_h(Wa1[(size_t)d * 512 + e]);
      }
      uint4 pk;
      pk.x = (uint)us[0] | ((uint)us[1] << 16);
      pk.y = (uint)us[2] | ((uint)us[3] << 16);
      pk.z = (uint)us[4] | ((uint)us[5] << 16);
      pk.w = (uint)us[6] | ((uint)us[7] << 16);
      *(uint4*)&Wa1swz[(size_t)id * 8] = pk;
    }
    return;
  }
  {
    // Wa2[512,256] -> [ks32][ct8][l64][j8]
    int sub = blk - 176;
    #pragma unroll
    for (int ko = 0; ko < 4; ++ko) {
      int id = sub * 1024 + ko * 256 + t;
      int ks = id >> 9, ct = (id >> 6) & 7, l = id & 63;
      ushort us[8];
      #pragma unroll
      for (int j = 0; j < 8; ++j) {
        int d = ks * 16 + ((l >> 5) * 4) + (j & 3) + ((j >> 2) * 8);
        int e = ct * 32 + (l & 31);
        us[j] = to_h(Wa2[(size_t)d * 256 + e]);
      }
      uint4 pk;
      pk.x = (uint)us[0] | ((uint)us[1] << 16);
      pk.y = (uint)us[2] | ((uint)us[3] << 16);
      pk.z = (uint)us[4] | ((uint)us[5] << 16);
      pk.w = (uint)us[6] | ((uint)us[7] << 16);
      *(uint4*)&Wa2swz[(size_t)id * 8] = pk;
    }
    return;
  }
}

// ---------------- fp16 MFMA scores: 2x2 micro-tile per wave, B prefetch ----------------
__global__ __launch_bounds__(256, 4) void k_scores_mfma(
    const ushort* __restrict__ h1p, const ushort* __restrict__ h2,
    const ushort* __restrict__ W2swz, const float* __restrict__ b2,
    const float* __restrict__ w3, const float* __restrict__ b3,
    float* __restrict__ scores)
{
  int bid = blockIdx.x;        // 2048: b(4) x r(4) x it(16) x jt(8)
  int jt = bid & 7;
  int it = (bid >> 3) & 15;
  int r  = (bid >> 7) & 3;
  int b  = bid >> 9;
  int t = threadIdx.x, w = t >> 6, l = t & 63;
  __shared__ uint h1u[8][132];
  __shared__ uint h2u[16][132];
  __shared__ float xch[4][2][2][16];

  const uint* h1g = (const uint*)h1p + ((size_t)((b * 4 + r) * 128 + it * 8)) * 128;
  const uint* h2g = (const uint*)h2  + ((size_t)((b * 4 + r) * 128 + jt * 16)) * 128;
  {
    int row = t >> 5, c4 = (t & 31) * 4;
    *(uint4*)&h1u[row][c4] = *(const uint4*)&h1g[row * 128 + c4];
    *(uint4*)&h2u[row][c4] = *(const uint4*)&h2g[row * 128 + c4];
    *(uint4*)&h2u[row + 8][c4] = *(const uint4*)&h2g[(row + 8) * 128 + c4];
  }

  f32x16 acc[2][2];
  #pragma unroll
  for (int i = 0; i < 2; ++i)
    #pragma unroll
    for (int c = 0; c < 2; ++c)
      #pragma unroll
      for (int e = 0; e < 16; ++e) acc[i][c][e] = 0.f;

  int rtp = w & 1, ctp = w >> 1;
  int hi2 = (l >> 5) * 2;
  int m31 = l & 31;
  int jrow = m31 & 15;
  int irow0 = (rtp * 2 + 0) * 2 + (m31 >> 4);
  int irow1 = (rtp * 2 + 1) * 2 + (m31 >> 4);
  const ushort* bptr = W2swz + r * (16 * 4 * 64 * 8) + (((ctp * 2) * 64 + l) * 8);

  __syncthreads();

  const uint* h1r0 = &h1u[irow0][0];
  const uint* h1r1 = &h1u[irow1][0];
  const uint* h2r  = &h2u[jrow][0];
  uint4 nb0 = *(const uint4*)&bptr[0];
  uint4 nb1 = *(const uint4*)&bptr[512];
  #pragma unroll 2
  for (int ks = 0; ks < 16; ++ks) {
    uint4 b0 = nb0, b1 = nb1;
    if (ks < 15) {
      nb0 = *(const uint4*)&bptr[(ks + 1) * 2048];
      nb1 = *(const uint4*)&bptr[(ks + 1) * 2048 + 512];
    }
    int u0 = ks * 8 + hi2;
    uint2 ya  = *(const uint2*)&h2r[u0];
    uint2 yb  = *(const uint2*)&h2r[u0 + 4];
    uint2 xa0 = *(const uint2*)&h1r0[u0];
    uint2 xb0 = *(const uint2*)&h1r0[u0 + 4];
    uint2 xa1 = *(const uint2*)&h1r1[u0];
    uint2 xb1 = *(const uint2*)&h1r1[u0 + 4];
    uint4 pk0, pk1;
    pk0.x = pk_relu(pk_add(xa0.x, ya.x));
    pk0.y = pk_relu(pk_add(xa0.y, ya.y));
    pk0.z = pk_relu(pk_add(xb0.x, yb.x));
    pk0.w = pk_relu(pk_add(xb0.y, yb.y));
    pk1.x = pk_relu(pk_add(xa1.x, ya.x));
    pk1.y = pk_relu(pk_add(xa1.y, ya.y));
    pk1.z = pk_relu(pk_add(xb1.x, yb.x));
    pk1.w = pk_relu(pk_add(xb1.y, yb.y));
    f16x8 af0 = __builtin_bit_cast(f16x8, pk0);
    f16x8 af1 = __builtin_bit_cast(f16x8, pk1);
    f16x8 bf0 = __builtin_bit_cast(f16x8, b0);
    f16x8 bf1 = __builtin_bit_cast(f16x8, b1);
    acc[0][0] = __builtin_amdgcn_mfma_f32_32x32x16_f16(af0, bf0, acc[0][0], 0, 0, 0);
    acc[0][1] = __builtin_amdgcn_mfma_f32_32x32x16_f16(af0, bf1, acc[0][1], 0, 0, 0);
    acc[1][0] = __builtin_amdgcn_mfma_f32_32x32x16_f16(af1, bf0, acc[1][0], 0, 0, 0);
    acc[1][1] = __builtin_amdgcn_mfma_f32_32x32x16_f16(af1, bf1, acc[1][1], 0, 0, 0);
  }

  float sp[2][16];
  #pragma unroll
  for (int i = 0; i < 2; ++i)
    #pragma unroll
    for (int g = 0; g < 16; ++g) sp[i][g] = 0.f;
  #pragma unroll
  for (int ctl = 0; ctl < 2; ++ctl) {
    int e = (ctp * 2 + ctl) * 32 + m31;
    float w3v = w3[r * 128 + e];
    float b2v = b2[r * 128 + e];
    #pragma unroll
    for (int i = 0; i < 2; ++i)
      #pragma unroll
      for (int g = 0; g < 16; ++g)
        sp[i][g] = fmaf(w3v, fmaxf(acc[i][ctl][g] + b2v, 0.f), sp[i][g]);
  }
  #pragma unroll
  for (int off = 16; off >= 1; off >>= 1)
    #pragma unroll
    for (int i = 0; i < 2; ++i)
      #pragma unroll
      for (int g = 0; g < 16; ++g)
        sp[i][g] += __shfl_xor(sp[i][g], off, 64);
  int hi = l >> 5;
  if (m31 == 0) {
    #pragma unroll
    for (int i = 0; i < 2; ++i)
      #pragma unroll
      for (int g = 0; g < 16; ++g)
        xch[w][i][hi][g] = sp[i][g];
  }
  __syncthreads();
  if (w < 2 && m31 == 0) {
    float b3v = b3[r];
    float* sc_base = scores + (((b * 4 + r) * 128 + it * 8) * 128) + jt * 16;
    #pragma unroll
    for (int i = 0; i < 2; ++i)
      #pragma unroll
      for (int g = 0; g < 16; ++g) {
        float s = xch[w][i][hi][g] + xch[w + 2][i][hi][g] + b3v;
        int p = (w * 2 + i) * 32 + (g & 3) + 8 * (g >> 2) + hi * 4;
        sc_base[(p >> 4) * 128 + (p & 15)] = s;
      }
  }
}

// ---------------- softmax + rel; 256 x 1-wave blocks, tree reductions ----------------
__global__ __launch_bounds__(64, 1) void k_softrel_mfma(
    const float* __restrict__ scores, const ushort* __restrict__ f2swz,
    ushort* __restrict__ all_rel_h)
{
  int bid = blockIdx.x;         // 256: b(4) x r(4) x nh(2) x rowq(4) x ctp(2)
  int ctp  = bid & 1;
  int rowq = (bid >> 1) & 3;
  int nh   = (bid >> 3) & 1;
  int r    = (bid >> 4) & 3;
  int b    = bid >> 6;
  int l = threadIdx.x;
  int row = rowq * 32 + (l & 31);
  const float* srow = scores + ((size_t)(b * 4 + r) * 128 + row) * 128;

  float p[128];
  #pragma unroll
  for (int q = 0; q < 32; ++q) {
    float4 v = *(const float4*)&srow[q * 4];
    p[q * 4 + 0] = v.x; p[q * 4 + 1] = v.y;
    p[q * 4 + 2] = v.z; p[q * 4 + 3] = v.w;
  }
  float mm[8];
  #pragma unroll
  for (int c = 0; c < 8; ++c) mm[c] = p[c * 16];
  #pragma unroll
  for (int k = 1; k < 16; ++k)
    #pragma unroll
    for (int c = 0; c < 8; ++c) mm[c] = fmaxf(mm[c], p[c * 16 + k]);
  float m = fmaxf(fmaxf(fmaxf(mm[0], mm[1]), fmaxf(mm[2], mm[3])),
                  fmaxf(fmaxf(mm[4], mm[5]), fmaxf(mm[6], mm[7])));
  float ss[8];
  #pragma unroll
  for (int c = 0; c < 8; ++c) ss[c] = 0.f;
  #pragma unroll
  for (int k = 0; k < 16; ++k)
    #pragma unroll
    for (int c = 0; c < 8; ++c) {
      p[c * 16 + k] = __expf(p[c * 16 + k] - m);
      ss[c] += p[c * 16 + k];
    }
  float sum = ((ss[0] + ss[1]) + (ss[2] + ss[3])) + ((ss[4] + ss[5]) + (ss[6] + ss[7]));
  float inv = 1.f / sum;
  uint preg[64];
  #pragma unroll
  for (int q = 0; q < 64; ++q)
    preg[q] = pack2(p[2 * q] * inv, p[2 * q + 1] * inv);

  f32x16 acc[2];
  #pragma unroll
  for (int c = 0; c < 2; ++c)
    #pragma unroll
    for (int e = 0; e < 16; ++e) acc[c][e] = 0.f;

  int hi2 = (l >> 5) * 2;
  const ushort* bbase = f2swz + (size_t)b * (8 * 8 * 64 * 8);
  #pragma unroll
  for (int ks = 0; ks < 8; ++ks) {
    int b2i = ks * 8 + hi2;
    uint4 pk = make_uint4(preg[b2i], preg[b2i + 1], preg[b2i + 4], preg[b2i + 5]);
    f16x8 af = __builtin_bit_cast(f16x8, pk);
    #pragma unroll
    for (int ctl = 0; ctl < 2; ++ctl) {
      int ct = nh * 4 + ctp * 2 + ctl;
      uint4 braw = *(const uint4*)&bbase[((ks * 8 + ct) * 64 + l) * 8];
      f16x8 bfr = __builtin_bit_cast(f16x8, braw);
      acc[ctl] = __builtin_amdgcn_mfma_f32_32x32x16_f16(af, bfr, acc[ctl], 0, 0, 0);
    }
  }

  ushort* dst = all_rel_h + (size_t)(b * 128) * 1024;
  int ebase = r * 256 + nh * 128 + ctp * 64 + (l & 31);
  int half4 = (l >> 5) << 2;
  #pragma unroll
  for (int ctl = 0; ctl < 2; ++ctl)
    #pragma unroll
    for (int g = 0; g < 16; ++g) {
      int i = rowq * 32 + (g & 3) + 8 * (g >> 2) + half4;
      dst[(size_t)i * 1024 + ebase + ctl * 32] = to_h(acc[ctl][g]);
    }
}

// ---------------- mlp1: hidden = relu(all_rel@Wa1+ba1), fp16 out ----------------
__global__ __launch_bounds__(256) void k_mlp1(
    const ushort* __restrict__ all_rel_h, const ushort* __restrict__ Wa1swz,
    const float* __restrict__ ba1, ushort* __restrict__ hiddenh)
{
  int cq = blockIdx.x, rt = blockIdx.y;
  int t = threadIdx.x, w = t >> 6, l = t & 63;
  __shared__ uint Ah[32][514];
  const uint* Ag = (const uint*)all_rel_h + (size_t)rt * 32 * 512;
  #pragma unroll
  for (int q = 0; q < 16; ++q) {
    int lin = q * 256 + t;
    int row = lin >> 7, c4 = (lin & 127) * 4;
    *(uint4*)&Ah[row][c4] = *(const uint4*)&Ag[row * 512 + c4];
  }
  __syncthreads();

  int m31 = l & 31, hi = l >> 5, hi2 = hi * 2;
  int ct = cq * 4 + w;
  f32x16 acc;
  #pragma unroll
  for (int e = 0; e < 16; ++e) acc[e] = 0.f;
  for (int ks = 0; ks < 64; ++ks) {
    int u0 = ks * 8 + hi2;
    uint2 xa = *(const uint2*)&Ah[m31][u0];
    uint2 xb = *(const uint2*)&Ah[m31][u0 + 4];
    uint4 a4 = make_uint4(xa.x, xa.y, xb.x, xb.y);
    f16x8 af = __builtin_bit_cast(f16x8, a4);
    uint4 braw = *(const uint4*)&Wa1swz[(size_t)((ks * 16 + ct) * 64 + l) * 8];
    f16x8 bfr = __builtin_bit_cast(f16x8, braw);
    acc = __builtin_amdgcn_mfma_f32_32x32x16_f16(af, bfr, acc, 0, 0, 0);
  }
  int e = ct * 32 + m31;
  float bv = ba1[e];
  #pragma unroll
  for (int g = 0; g < 16; ++g) {
    int row = (g & 3) + 8 * (g >> 2) + 4 * hi;
    hiddenh[(size_t)(rt * 32 + row) * 512 + e] = to_h(fmaxf(acc[g] + bv, 0.f));
  }
}

// ---------------- mlp2: out = hidden@Wa2+ba2, fp32 out ----------------
__global__ __launch_bounds__(256) void k_mlp2(
    const ushort* __restrict__ hiddenh, const ushort* __restrict__ Wa2swz,
    const float* __restrict__ ba2, float* __restrict__ out)
{
  int cq = blockIdx.x, rt = blockIdx.y;
  int t = threadIdx.x, w = t >> 6, l = t & 63;
  __shared__ uint Ah[32][258];
  const uint* Ag = (const uint*)hiddenh + (size_t)rt * 32 * 256;
  #pragma unroll
  for (int q = 0; q < 8; ++q) {
    int lin = q * 256 + t;
    int row = lin >> 6, c4 = (lin & 63) * 4;
    *(uint4*)&Ah[row][c4] = *(const uint4*)&Ag[row * 256 + c4];
  }
  __syncthreads();

  int m31 = l & 31, hi = l >> 5, hi2 = hi * 2;
  int ct = cq * 4 + w;
  f32x16 acc;
  #pragma unroll
  for (int e = 0; e < 16; ++e) acc[e] = 0.f;
  for (int ks = 0; ks < 32; ++ks) {
    int u0 = ks * 8 + hi2;
    uint2 xa = *(const uint2*)&Ah[m31][u0];
    uint2 xb = *(const uint2*)&Ah[m31][u0 + 4];
    uint4 a4 = make_uint4(xa.x, xa.y, xb.x, xb.y);
    f16x8 af = __builtin_bit_cast(f16x8, a4);
    uint4 braw = *(const uint4*)&Wa2swz[(size_t)((ks * 8 + ct) * 64 + l) * 8];
    f16x8 bfr = __builtin_bit_cast(f16x8, braw);
    acc = __builtin_amdgcn_mfma_f32_32x32x16_f16(af, bfr, acc, 0, 0, 0);
  }
  int e = ct * 32 + m31;
  float bv = ba2[e];
  #pragma unroll
  for (int g = 0; g < 16; ++g) {
    int row = (g & 3) + 8 * (g >> 2) + 4 * hi;
    out[(size_t)(rt * 32 + row) * 256 + e] = acc[g] + bv;
  }
}

extern "C" void kernel_launch(void* const* d_in, const int* in_sizes, int n_in,
                              void* d_out, int out_size, void* d_ws, size_t ws_size,
                              hipStream_t stream) {
  const float* f1  = (const float*)d_in[0];
  const float* f2  = (const float*)d_in[1];
  const float* W1  = (const float*)d_in[2];
  const float* b1  = (const float*)d_in[3];
  const float* W2  = (const float*)d_in[4];
  const float* b2  = (const float*)d_in[5];
  const float* w3  = (const float*)d_in[6];
  const float* b3  = (const float*)d_in[7];
  const float* Wa1 = (const float*)d_in[8];
  const float* ba1 = (const float*)d_in[9];
  const float* Wa2 = (const float*)d_in[10];
  const float* ba2 = (const float*)d_in[11];
  float* out = (float*)d_out;
  float* ws = (float*)d_ws;

  ushort* h1p      = (ushort*)ws;                 // @0,     1MB
  ushort* h2       = (ushort*)(ws + 262144);      // @1MB,   1MB
  float*  scores   = ws + 524288;                 // @2MB,   1MB
  ushort* all_relh = (ushort*)(ws + 786432);      // @3MB,   1MB
  ushort* W2swz    = (ushort*)(ws + 1048576);     // @4MB,   256KB
  ushort* f2swz    = (ushort*)(ws + 1114112);     // @4.25MB,256KB
  ushort* Wa1swz   = (ushort*)(ws + 1179648);     // @4.5MB, 1MB
  ushort* Wa2swz   = (ushort*)(ws + 1441792);     // @5.5MB, 256KB
  ushort* hiddenh  = (ushort*)(ws + 1507328);     // @5.75MB,512KB

  hipLaunchKernelGGL(k_prepproj, dim3(192), dim3(256), 0, stream,
                     f1, f2, W1, b1, W2, Wa1, Wa2,
                     W2swz, f2swz, Wa1swz, Wa2swz, h1p, h2);
  hipLaunchKernelGGL(k_scores_mfma, dim3(2048), dim3(256), 0, stream,
                     h1p, h2, W2swz, b2, w3, b3, scores);
  hipLaunchKernelGGL(k_softrel_mfma, dim3(256), dim3(64), 0, stream,
                     scores, f2swz, all_relh);
  hipLaunchKernelGGL(k_mlp1, dim3(4, 16), dim3(256), 0, stream,
                     all_relh, Wa1swz, ba1, hiddenh);
  hipLaunchKernelGGL(k_mlp2, dim3(2, 16), dim3(256), 0, stream,
                     hiddenh, Wa2swz, ba2, out);
}